// Round 10
// baseline (113.770 us; speedup 1.0000x reference)
//
#include <hip/hip_runtime.h>
#include <hip/hip_bf16.h>
#include <stdint.h>

// ---------------- problem constants ----------------
#define BATCH 16
#define CDIM  1024
#define FWID  32
#define HW    1024
#define NA    1024
#define NTOT  (BATCH*NA)    // 16384
#define NCHUNK 16           // 8 mi-tiles * 2 wc waves = 16 chunks of 64 cols
#define MARGIN 0.6f

typedef __bf16 bf16x8 __attribute__((ext_vector_type(8)));
typedef float  f32x4  __attribute__((ext_vector_type(4)));
typedef unsigned short us4 __attribute__((ext_vector_type(4)));
typedef unsigned short us8 __attribute__((ext_vector_type(8)));
typedef float  f4     __attribute__((ext_vector_type(4)));

template<int OFF>
__device__ __forceinline__ us4 tr_read(uint32_t addr){
  us4 r;
  asm volatile("ds_read_b64_tr_b16 %0, %1 offset:%2" : "=v"(r) : "v"(addr), "n"(OFF));
  return r;
}

__device__ __forceinline__ void gload16(const unsigned short* g, unsigned short* l){
  __builtin_amdgcn_global_load_lds((const __attribute__((address_space(1))) void*)g,
                                   (__attribute__((address_space(3))) void*)l, 16, 0, 0);
}

union FragU  { us4 h[2]; bf16x8 v; };
union FragU8 { us8 u;    bf16x8 v; };

__device__ __forceinline__ void ins3(float& a, float& b, float& c, float v){
  if (v < c){
    c = v;
    if (c < b){ float t=b; b=c; c=t;
      if (b < a){ t=a; a=b; b=t; }
    }
  }
}

#define MFMA __builtin_amdgcn_mfma_f32_16x16x32_bf16

// ---------------------------------------------------------------------------
// Pass 1 (v2): fp32 [c][hw] -> bf16 [hw][c] via LDS-staged transpose.
// grid: e(2) x b(16) x hwT(16: 64hw) x cT(8: 128c) = 4096 blocks, 256 thr.
// Read: per c-row, 16 lanes x f4 = 256B contiguous.  Write: per hw-row,
// 4 threads x 64B = 256B contiguous.  LDS tile [64][136] us (pad 8).
// ---------------------------------------------------------------------------
__global__ __launch_bounds__(256)
void convert_transpose2(const float* __restrict__ S, const float* __restrict__ R,
                        unsigned short* __restrict__ tS, unsigned short* __restrict__ tR,
                        float* __restrict__ pnorm){
  __shared__ unsigned short tile[64*136];   // 34816 B
  __shared__ float nsq[64][17];             // 4352 B

  const int blk = blockIdx.x;
  const int e   = blk >> 11;
  const int b   = (blk >> 7) & 15;
  const int hwT = (blk >> 3) & 15;
  const int cT  = blk & 7;
  const float* src = (e ? R : S) + (size_t)b*CDIM*HW;
  unsigned short* dst = (e ? tR : tS) + (size_t)b*HW*CDIM;

  const int t  = threadIdx.x;
  const int gi = t >> 4;          // c-octet 0..15
  const int li = t & 15;          // hw quad: hw = hwT*64 + li*4 + j
  const int hwb = hwT*64 + li*4;

  us8 hj0, hj1, hj2, hj3;
  float sq0=0.f, sq1=0.f, sq2=0.f, sq3=0.f;
  #pragma unroll
  for (int i = 0; i < 8; ++i){
    const int c = cT*128 + gi*8 + i;
    const f4 v = *(const f4*)&src[(size_t)c*HW + hwb];
    __hip_bfloat16 h0 = __float2bfloat16(v[0]);
    __hip_bfloat16 h1 = __float2bfloat16(v[1]);
    __hip_bfloat16 h2 = __float2bfloat16(v[2]);
    __hip_bfloat16 h3 = __float2bfloat16(v[3]);
    hj0[i] = __builtin_bit_cast(unsigned short, h0);
    hj1[i] = __builtin_bit_cast(unsigned short, h1);
    hj2[i] = __builtin_bit_cast(unsigned short, h2);
    hj3[i] = __builtin_bit_cast(unsigned short, h3);
    const float g0 = __bfloat162float(h0), g1 = __bfloat162float(h1);
    const float g2 = __bfloat162float(h2), g3 = __bfloat162float(h3);
    sq0 = fmaf(g0,g0,sq0); sq1 = fmaf(g1,g1,sq1);
    sq2 = fmaf(g2,g2,sq2); sq3 = fmaf(g3,g3,sq3);
  }
  *(us8*)&tile[(li*4+0)*136 + gi*8] = hj0;
  *(us8*)&tile[(li*4+1)*136 + gi*8] = hj1;
  *(us8*)&tile[(li*4+2)*136 + gi*8] = hj2;
  *(us8*)&tile[(li*4+3)*136 + gi*8] = hj3;
  nsq[li*4+0][gi] = sq0;
  nsq[li*4+1][gi] = sq1;
  nsq[li*4+2][gi] = sq2;
  nsq[li*4+3][gi] = sq3;
  __syncthreads();

  // write phase: 4 threads per hw-row, 32 c's (64B) each
  const int hw_l = t >> 2;
  const int cg   = t & 3;
  const unsigned short* row = &tile[hw_l*136 + cg*32];
  const us8 o0 = *(const us8*)(row);
  const us8 o1 = *(const us8*)(row + 8);
  const us8 o2 = *(const us8*)(row + 16);
  const us8 o3 = *(const us8*)(row + 24);
  unsigned short* drow = dst + (size_t)(hwT*64 + hw_l)*CDIM + cT*128 + cg*32;
  *(us8*)(drow)      = o0;
  *(us8*)(drow + 8)  = o1;
  *(us8*)(drow + 16) = o2;
  *(us8*)(drow + 24) = o3;

  if (t < 64){
    float a = 0.f;
    #pragma unroll
    for (int g = 0; g < 16; ++g) a += nsq[t][g];
    pnorm[((size_t)(e*16 + b)*8 + cT)*HW + hwT*64 + t] = a;
  }
}

__global__ __launch_bounds__(256)
void norm_reduce(const float* __restrict__ pnorm, float* __restrict__ snorm){
  const int eb = blockIdx.x;
  const int t  = threadIdx.x;
  #pragma unroll
  for (int r = 0; r < 4; ++r){
    const int hw = r*256 + t;
    float a = 0.f;
    #pragma unroll
    for (int ct = 0; ct < 8; ++ct)
      a += pnorm[((size_t)eb*8 + ct)*HW + hw];
    snorm[(size_t)eb*HW + hw] = sqrtf(a);
  }
}

// ---------------------------------------------------------------------------
// Pass 2 (v6): v5's proven schedule (3-buf, depth-2 prefetch, counted
// vmcnt(4), 1 barrier/tile, 0-conflict swizzle, cheap epilogue) at 128x128
// tile / 4 waves / 50KB LDS -> 3 blocks/CU (12 waves/CU) for cross-block
// overlap of staging and compute.  grid 1024 = b(16) x ni(8) x mi(8).
// ---------------------------------------------------------------------------
__global__ __launch_bounds__(256, 3)
void fused_gemm_top3_v6(const unsigned short* __restrict__ tS,
                        const unsigned short* __restrict__ tR,
                        const float* __restrict__ snorm,
                        const int*   __restrict__ anchor,
                        const int*   __restrict__ posidx,
                        float* __restrict__ wtop,   // [NTOT][NCHUNK][3]
                        float* __restrict__ wpos)   // [NTOT]
{
  // A: us [0, 12288) = 3 bufs x 4096 us (8KB: 128 rows x 32 k);
  // B: us [12288, 24576).  Total 48KB + 2KB aux.
  __shared__ unsigned short stage[24576];
  __shared__ int   p_lds[128], q_lds[128];
  __shared__ float nAs[128], nBs[128];      // RECIPROCAL norms

  const int t = threadIdx.x;
  const uint32_t bid = blockIdx.x;
  const uint32_t L = (bid & 7u)*128u + (bid >> 3);   // XCD swizzle (1024%8==0)
  const int b  = L >> 6;
  const int ni = (L >> 3) & 7;
  const int mi = L & 7;

  const unsigned short* SbT = tS + (size_t)b*HW*CDIM;
  const unsigned short* RbT = tR + (size_t)b*HW*CDIM;

  if (t < 128){
    const int n_g = ni*128 + t;
    const int* ap = anchor + (size_t)(b*NA + n_g)*3;
    const int* pp = posidx + (size_t)(b*NA + n_g)*3;
    const int pv = ap[2]*FWID + ap[1];
    p_lds[t] = pv;
    q_lds[t] = pp[2]*FWID + pp[1];
    nAs[t] = 1.0f / snorm[(size_t)b*HW + pv];
  } else {
    nBs[t-128] = 1.0f / snorm[(size_t)(BATCH + b)*HW + mi*128 + (t-128)];
  }
  __syncthreads();

  const int l  = t & 63;
  const int w  = t >> 6;            // 0..3
  const int wr = w >> 1, wc = w & 1;

  // staging: wave w covers rows w*32..w*32+31; inst i: row = w*32+i*16+(l>>2),
  // stored chunk pc = l&3; pre-swizzled global kc = pc ^ ((row>>1)&3).
  const int gkc = (l&3) ^ ((l>>3)&3);
  const int r0  = w*32 + (l>>2);
  const int r1  = r0 + 16;
  const unsigned short* gA0 = SbT + (size_t)p_lds[r0]*CDIM + gkc*8;
  const unsigned short* gA1 = SbT + (size_t)p_lds[r1]*CDIM + gkc*8;
  const unsigned short* gB0 = RbT + (size_t)(mi*128 + r0)*CDIM + gkc*8;
  const unsigned short* gB1 = RbT + (size_t)(mi*128 + r1)*CDIM + gkc*8;
  unsigned short* lA = &stage[w*1024];
  unsigned short* lB = &stage[12288 + w*1024];

  // frag read: row = base16 + (l&15), kc = l>>4 -> swz = (l>>4) ^ ((l>>1)&3)
  const int fbase = (l&15)*32 + (((l>>4) ^ ((l>>1)&3))*8);
  const int abase = wr*2048 + fbase;             // wr*64 rows * 32 us
  const int bbase = 12288 + wc*2048 + fbase;     // wc*64 rows * 32 us

  f32x4 acc[4][4];
  #pragma unroll
  for (int i=0;i<4;i++){
    #pragma unroll
    for (int j=0;j<4;j++){ f32x4 z = {0.f,0.f,0.f,0.f}; acc[i][j] = z; }
  }

  auto stage_fn = [&](int bo, int kt){
    const int ko = kt*32;
    gload16(gA0 + ko, lA + bo);
    gload16(gA1 + ko, lA + bo + 512);
    gload16(gB0 + ko, lB + bo);
    gload16(gB1 + ko, lB + bo + 512);
  };

  auto compute = [&](int bo){
    FragU8 Bf[4], Af[4];
    #pragma unroll
    for (int fb=0; fb<4; ++fb) Bf[fb].u = *(const us8*)&stage[bbase + bo + fb*512];
    #pragma unroll
    for (int fa=0; fa<4; ++fa) Af[fa].u = *(const us8*)&stage[abase + bo + fa*512];
    #pragma unroll
    for (int fa=0; fa<4; ++fa){
      #pragma unroll
      for (int fb=0; fb<4; ++fb)
        acc[fa][fb] = MFMA(Af[fa].v, Bf[fb].v, acc[fa][fb], 0,0,0);
    }
  };

  // ---- main K loop: 32 tiles, 3 bufs, depth-2, 1 barrier/tile ----
  stage_fn(0, 0);
  stage_fn(4096, 1);
  int oc = 0, on = 4096, on2 = 8192;
  for (int kt = 0; kt < 32; ++kt){
    if (kt < 31) asm volatile("s_waitcnt vmcnt(4)" ::: "memory");
    else         asm volatile("s_waitcnt vmcnt(0)" ::: "memory");
    asm volatile("s_waitcnt lgkmcnt(0)" ::: "memory");
    __builtin_amdgcn_s_barrier();
    if (kt < 30) stage_fn(on2, kt+2);
    compute(oc);
    const int tmp = oc; oc = on; on = on2; on2 = tmp;
  }

  // ---- epilogue: reciprocal norms + LDS two-phase top3 ----
  __syncthreads();   // stage free -> reuse as scratch
  float* tls = (float*)&stage[0] + (size_t)w*1152;   // 16 rows x 17 f4 / wave

  float rinv[4];
  #pragma unroll
  for (int fb=0; fb<4; ++fb) rinv[fb] = nBs[wc*64 + fb*16 + (l&15)];

  #pragma unroll
  for (int fa=0; fa<4; ++fa){
    #pragma unroll
    for (int r=0; r<4; ++r){
      const int rg    = (l>>4)*4 + r;
      const int row_l = wr*64 + fa*16 + rg;
      const float ain = nAs[row_l];
      const float v0 = acc[fa][0][r] * ain * rinv[0];
      const float v1 = acc[fa][1][r] * ain * rinv[1];
      const float v2 = acc[fa][2][r] * ain * rinv[2];
      const float v3 = acc[fa][3][r] * ain * rinv[3];

      const int n_g = ni*128 + row_l;
      const int q   = q_lds[row_l];
      const int ql  = q - (mi*128 + wc*64);
      if (ql >= 0 && ql < 64 && (ql & 15) == (l & 15)){
        const int sel = ql >> 4;
        const float pv = sel==0 ? v0 : sel==1 ? v1 : sel==2 ? v2 : v3;
        wpos[b*NA + n_g] = pv;
      }

      float x=1e30f, y=1e30f, z=1e30f;
      ins3(x,y,z,v0); ins3(x,y,z,v1); ins3(x,y,z,v2); ins3(x,y,z,v3);
      f4 tr = {x, y, z, 0.f};
      *(f4*)(tls + (rg*17 + (l&15))*4) = tr;
    }
    asm volatile("s_waitcnt lgkmcnt(0)" ::: "memory");
    __builtin_amdgcn_sched_barrier(0);

    {
      const int rr = l >> 2;
      const float* rbp = tls + (rr*17 + (l&3)*4)*4;
      const f4 t0 = *(const f4*)(rbp);
      const f4 t1 = *(const f4*)(rbp + 4);
      const f4 t2 = *(const f4*)(rbp + 8);
      const f4 t3 = *(const f4*)(rbp + 12);
      float x = t0[0], y = t0[1], z = t0[2];
      ins3(x,y,z,t1[0]); ins3(x,y,z,t1[1]); ins3(x,y,z,t1[2]);
      ins3(x,y,z,t2[0]); ins3(x,y,z,t2[1]); ins3(x,y,z,t2[2]);
      ins3(x,y,z,t3[0]); ins3(x,y,z,t3[1]); ins3(x,y,z,t3[2]);
      #pragma unroll
      for (int m=1; m<4; m<<=1){
        const float ox = __shfl_xor(x, m);
        const float oy = __shfl_xor(y, m);
        const float oz = __shfl_xor(z, m);
        ins3(x,y,z,ox); ins3(x,y,z,oy); ins3(x,y,z,oz);
      }
      if ((l & 3) == 0){
        const int n_g = ni*128 + wr*64 + fa*16 + rr;
        float* dst = wtop + ((size_t)(b*NA + n_g)*NCHUNK + (mi*2 + wc))*3;
        dst[0]=x; dst[1]=y; dst[2]=z;
      }
    }
    asm volatile("s_waitcnt lgkmcnt(0)" ::: "memory");
    __builtin_amdgcn_sched_barrier(0);
  }
}

// ---------------------------------------------------------------------------
// v1 (verified) fused kernel — fallback when workspace is too small.
// ---------------------------------------------------------------------------
__global__ __launch_bounds__(256)
void fused_gemm_top3_v1(const float* __restrict__ sketch,
                        const float* __restrict__ refk,
                        const int*   __restrict__ anchor,
                        const int*   __restrict__ posidx,
                        float* __restrict__ wtop,
                        float* __restrict__ wpos)
{
  __shared__ union {
    unsigned short stage[16384];
    struct { float nA[16][128]; float nB[16][128]; } nrm;
  } sh;
  __shared__ int   p_lds[128];
  __shared__ float nA2[128], nB2[128];

  const int t = threadIdx.x;
  const uint32_t bid = blockIdx.x;
  const uint32_t L = (bid & 7u)*128u + (bid >> 3);
  const int b  = L >> 6;
  const int ni = (L >> 3) & 7;
  const int mi = L & 7;

  const float* Sb = sketch + (size_t)b*CDIM*HW;
  const float* Rb = refk   + (size_t)b*CDIM*HW;

  if (t < 128){
    const int n_g = ni*128 + t;
    const int* ap = anchor + (size_t)(b*NA + n_g)*3;
    p_lds[t] = ap[2]*FWID + ap[1];
  }
  __syncthreads();
  const int p0 = p_lds[0];
  int okf = 1;
  if (t < 128) okf = (p_lds[t] == p0 + t);
  const int contig = __syncthreads_and(okf);

  const int colg = (t & 15)*8;
  const int rowg = t >> 4;
  const int mbase = mi*128;

  const int l  = t & 63;
  const int w  = t >> 6;
  const int wr = w >> 1, wc = w & 1;
  const uint32_t sh_base = (uint32_t)(uintptr_t)&sh.stage[0];
  const uint32_t laneA = ((uint32_t)(l>>4))*2048u + (uint32_t)wr*512u + (uint32_t)(l&15)*8u;
  const uint32_t laneB = ((uint32_t)(l>>4))*2048u + (uint32_t)wc*512u + (uint32_t)(l&15)*8u;
  const int off0 = ((rowg>>2)*8 + (colg>>4))*64 + (rowg&3)*16 + (colg&15);

  f32x4 acc[4][4];
  #pragma unroll
  for (int i=0;i<4;i++){
    #pragma unroll
    for (int j=0;j<4;j++){ f32x4 z = {0.f,0.f,0.f,0.f}; acc[i][j] = z; }
  }

  float sqA[8] = {0,0,0,0,0,0,0,0};
  float sqB[8] = {0,0,0,0,0,0,0,0};
  f4 ra[4], rb[4];

  auto load_tile = [&](int kt){
    const int c0 = kt*32 + rowg;
    const float* SA = Sb + (size_t)c0*HW;
    const float* RB = Rb + (size_t)c0*HW + mbase + colg;
    if (contig){
      const float* pA = SA + p0 + colg;
      ra[0] = *(const f4*)(pA);
      ra[1] = *(const f4*)(pA + 4);
      ra[2] = *(const f4*)(pA + 16*HW);
      ra[3] = *(const f4*)(pA + 16*HW + 4);
    } else {
      float* raf = (float*)ra;
      #pragma unroll
      for (int i=0;i<8;i++){
        const int pc = p_lds[colg + i];
        raf[i]   = SA[pc];
        raf[8+i] = SA[16*HW + pc];
      }
    }
    rb[0] = *(const f4*)(RB);
    rb[1] = *(const f4*)(RB + 4);
    rb[2] = *(const f4*)(RB + 16*HW);
    rb[3] = *(const f4*)(RB + 16*HW + 4);
  };

  auto cvt_store = [&](int buf){
    const float* raf = (const float*)ra;
    const float* rbf = (const float*)rb;
    us8 pk;
    #pragma unroll
    for (int i=0;i<8;i++){
      __hip_bfloat16 h = __float2bfloat16(raf[i]);
      pk[i] = __builtin_bit_cast(unsigned short, h);
      const float g = __bfloat162float(h);
      sqA[i] = fmaf(g, g, sqA[i]);
    }
    *(us8*)&sh.stage[buf*4096 + off0] = pk;
    #pragma unroll
    for (int i=0;i<8;i++){
      __hip_bfloat16 h = __float2bfloat16(raf[8+i]);
      pk[i] = __builtin_bit_cast(unsigned short, h);
      const float g = __bfloat162float(h);
      sqA[i] = fmaf(g, g, sqA[i]);
    }
    *(us8*)&sh.stage[buf*4096 + off0 + 2048] = pk;
    #pragma unroll
    for (int i=0;i<8;i++){
      __hip_bfloat16 h = __float2bfloat16(rbf[i]);
      pk[i] = __builtin_bit_cast(unsigned short, h);
      const float g = __bfloat162float(h);
      sqB[i] = fmaf(g, g, sqB[i]);
    }
    *(us8*)&sh.stage[8192 + buf*4096 + off0] = pk;
    #pragma unroll
    for (int i=0;i<8;i++){
      __hip_bfloat16 h = __float2bfloat16(rbf[8+i]);
      pk[i] = __builtin_bit_cast(unsigned short, h);
      const float g = __bfloat162float(h);
      sqB[i] = fmaf(g, g, sqB[i]);
    }
    *(us8*)&sh.stage[8192 + buf*4096 + off0 + 2048] = pk;
  };

  auto compute = [&](int buf){
    const uint32_t aaddr = sh_base + (uint32_t)buf*8192u + laneA;
    const uint32_t baddr = sh_base + 16384u + (uint32_t)buf*8192u + laneB;
    FragU A0,A1,A2,A3,B0,B1,B2,B3;
    A0.h[0]=tr_read<0>(aaddr);    A0.h[1]=tr_read<1024>(aaddr);
    A1.h[0]=tr_read<128>(aaddr);  A1.h[1]=tr_read<1152>(aaddr);
    A2.h[0]=tr_read<256>(aaddr);  A2.h[1]=tr_read<1280>(aaddr);
    A3.h[0]=tr_read<384>(aaddr);  A3.h[1]=tr_read<1408>(aaddr);
    B0.h[0]=tr_read<0>(baddr);    B0.h[1]=tr_read<1024>(baddr);
    B1.h[0]=tr_read<128>(baddr);  B1.h[1]=tr_read<1152>(baddr);
    B2.h[0]=tr_read<256>(baddr);  B2.h[1]=tr_read<1280>(baddr);
    B3.h[0]=tr_read<384>(baddr);  B3.h[1]=tr_read<1408>(baddr);
    asm volatile("s_waitcnt lgkmcnt(0)" ::: "memory");
    __builtin_amdgcn_sched_barrier(0);
    acc[0][0]=MFMA(A0.v,B0.v,acc[0][0],0,0,0);
    acc[0][1]=MFMA(A0.v,B1.v,acc[0][1],0,0,0);
    acc[0][2]=MFMA(A0.v,B2.v,acc[0][2],0,0,0);
    acc[0][3]=MFMA(A0.v,B3.v,acc[0][3],0,0,0);
    acc[1][0]=MFMA(A1.v,B0.v,acc[1][0],0,0,0);
    acc[1][1]=MFMA(A1.v,B1.v,acc[1][1],0,0,0);
    acc[1][2]=MFMA(A1.v,B2.v,acc[1][2],0,0,0);
    acc[1][3]=MFMA(A1.v,B3.v,acc[1][3],0,0,0);
    acc[2][0]=MFMA(A2.v,B0.v,acc[2][0],0,0,0);
    acc[2][1]=MFMA(A2.v,B1.v,acc[2][1],0,0,0);
    acc[2][2]=MFMA(A2.v,B2.v,acc[2][2],0,0,0);
    acc[2][3]=MFMA(A2.v,B3.v,acc[2][3],0,0,0);
    acc[3][0]=MFMA(A3.v,B0.v,acc[3][0],0,0,0);
    acc[3][1]=MFMA(A3.v,B1.v,acc[3][1],0,0,0);
    acc[3][2]=MFMA(A3.v,B2.v,acc[3][2],0,0,0);
    acc[3][3]=MFMA(A3.v,B3.v,acc[3][3],0,0,0);
  };

  load_tile(0);
  cvt_store(0);
  __syncthreads();
  int buf = 0;
  for (int kt = 0; kt < 32; ++kt){
    if (kt < 31) load_tile(kt+1);
    compute(buf);
    if (kt < 31) cvt_store(buf^1);
    __syncthreads();
    buf ^= 1;
  }

  #pragma unroll
  for (int i=0;i<8;i++) sh.nrm.nA[rowg][colg+i] = sqA[i];
  #pragma unroll
  for (int i=0;i<8;i++) sh.nrm.nB[rowg][colg+i] = sqB[i];
  __syncthreads();
  if (t < 128){
    float s = 0.f;
    #pragma unroll
    for (int r=0;r<16;r++) s += sh.nrm.nA[r][t];
    nA2[t] = s;
  } else {
    const int c2 = t - 128;
    float s = 0.f;
    #pragma unroll
    for (int r=0;r<16;r++) s += sh.nrm.nB[r][c2];
    nB2[c2] = s;
  }
  __syncthreads();

  float rncol[4];
  #pragma unroll
  for (int nf=0;nf<4;nf++) rncol[nf] = sqrtf(nB2[wc*64 + nf*16 + (l&15)]);

  #pragma unroll
  for (int mf=0; mf<4; ++mf){
    #pragma unroll
    for (int r=0; r<4; ++r){
      const int row_l = wr*64 + mf*16 + (l>>4)*4 + r;
      const int n_g   = ni*128 + row_l;
      const float an  = sqrtf(nA2[row_l]);
      const float v0 = acc[mf][0][r] / fmaxf(an*rncol[0], 1e-8f);
      const float v1 = acc[mf][1][r] / fmaxf(an*rncol[1], 1e-8f);
      const float v2 = acc[mf][2][r] / fmaxf(an*rncol[2], 1e-8f);
      const float v3 = acc[mf][3][r] / fmaxf(an*rncol[3], 1e-8f);

      const int* pp = posidx + (size_t)(b*NA + n_g)*3;
      const int q  = pp[2]*FWID + pp[1];
      const int ql = q - (mbase + wc*64);
      if (ql >= 0 && ql < 64 && (ql & 15) == (l & 15)){
        const int sel = ql >> 4;
        const float pv = sel==0 ? v0 : sel==1 ? v1 : sel==2 ? v2 : v3;
        wpos[b*NA + n_g] = pv;
      }

      float x=1e30f, y=1e30f, z=1e30f;
      ins3(x,y,z,v0); ins3(x,y,z,v1); ins3(x,y,z,v2); ins3(x,y,z,v3);
      #pragma unroll
      for (int m=1; m<16; m<<=1){
        const float ox = __shfl_xor(x, m);
        const float oy = __shfl_xor(y, m);
        const float oz = __shfl_xor(z, m);
        ins3(x,y,z,ox); ins3(x,y,z,oy); ins3(x,y,z,oz);
      }
      if ((l & 15) == 0){
        float* dst = wtop + ((size_t)(b*NA + n_g)*NCHUNK + (mi*2 + wc))*3;
        dst[0]=x; dst[1]=y; dst[2]=z;
      }
    }
  }
}

// ---------------------------------------------------------------------------
__global__ __launch_bounds__(256)
void merge_top3(const float* __restrict__ wtop, const float* __restrict__ wpos,
                float* __restrict__ partial){
  __shared__ float red[256];
  const int id = blockIdx.x*256 + threadIdx.x;
  const float* src = wtop + (size_t)id*(NCHUNK*3);
  float x=1e30f, y=1e30f, z=1e30f;
  #pragma unroll
  for (int i=0;i<NCHUNK*3;i++) ins3(x,y,z, src[i]);
  const float loss = fmaxf((x+y+z) - wpos[id] + MARGIN, 0.0f);
  red[threadIdx.x] = loss;
  __syncthreads();
  for (int s=128; s>0; s>>=1){
    if (threadIdx.x < s) red[threadIdx.x] += red[threadIdx.x+s];
    __syncthreads();
  }
  if (threadIdx.x == 0) partial[blockIdx.x] = red[0];
}

__global__ void final_sum(const float* __restrict__ partial, float* __restrict__ out){
  float v = partial[threadIdx.x];
  #pragma unroll
  for (int off=32; off>0; off>>=1) v += __shfl_down(v, off);
  if (threadIdx.x == 0) out[0] = v / (1e-6f + (float)NTOT);
}

// ---------------------------------------------------------------------------
extern "C" void kernel_launch(void* const* d_in, const int* in_sizes, int n_in,
                              void* d_out, int out_size, void* d_ws, size_t ws_size,
                              hipStream_t stream){
  const float* sketch = (const float*)d_in[0];
  const float* refk   = (const float*)d_in[1];
  const int*   anchor = (const int*)d_in[2];
  const int*   posidx = (const int*)d_in[3];
  float* out = (float*)d_out;

  float* wtop    = (float*)d_ws;                       // NTOT*NCHUNK*3 floats
  float* wpos    = wtop + (size_t)NTOT*NCHUNK*3;       // NTOT floats
  float* partial = wpos + NTOT;                        // 64 floats (+pad)
  unsigned short* tS = (unsigned short*)(partial + 256);
  unsigned short* tR = tS + (size_t)BATCH*HW*CDIM;
  float* pnorm = (float*)(tR + (size_t)BATCH*HW*CDIM); // 32*8*1024 floats
  float* snorm = pnorm + (size_t)32*8*1024;            // 32*1024 floats
  const size_t need = (size_t)((char*)(snorm + 32*1024) - (char*)d_ws);

  if (ws_size >= need){
    convert_transpose2<<<dim3(4096), dim3(256), 0, stream>>>(sketch, refk, tS, tR, pnorm);
    norm_reduce<<<dim3(32), dim3(256), 0, stream>>>(pnorm, snorm);
    fused_gemm_top3_v6<<<dim3(1024), dim3(256), 0, stream>>>(tS, tR, snorm, anchor, posidx, wtop, wpos);
  } else {
    fused_gemm_top3_v1<<<dim3(1024), dim3(256), 0, stream>>>(sketch, refk, anchor, posidx, wtop, wpos);
  }
  merge_top3<<<dim3(64), dim3(256), 0, stream>>>(wtop, wpos, partial);
  final_sum<<<dim3(1), dim3(64), 0, stream>>>(partial, out);
}

// Round 11
// 101.659 us; speedup vs baseline: 1.1191x; 1.1191x over previous
//
#include <hip/hip_runtime.h>
#include <hip/hip_bf16.h>
#include <stdint.h>

// ---------------- problem constants ----------------
#define BATCH 16
#define CDIM  1024
#define FWID  32
#define HW    1024
#define NA    1024
#define NTOT  (BATCH*NA)    // 16384
#define NCHUNK 16           // 4 mi-tiles * 4 wc waves = 16 chunks of 64 cols
#define MARGIN 0.6f

typedef __bf16 bf16x8 __attribute__((ext_vector_type(8)));
typedef float  f32x4  __attribute__((ext_vector_type(4)));
typedef unsigned short us4 __attribute__((ext_vector_type(4)));
typedef unsigned short us8 __attribute__((ext_vector_type(8)));
typedef float  f4     __attribute__((ext_vector_type(4)));

template<int OFF>
__device__ __forceinline__ us4 tr_read(uint32_t addr){
  us4 r;
  asm volatile("ds_read_b64_tr_b16 %0, %1 offset:%2" : "=v"(r) : "v"(addr), "n"(OFF));
  return r;
}

__device__ __forceinline__ void gload16(const unsigned short* g, unsigned short* l){
  __builtin_amdgcn_global_load_lds((const __attribute__((address_space(1))) void*)g,
                                   (__attribute__((address_space(3))) void*)l, 16, 0, 0);
}

union FragU  { us4 h[2]; bf16x8 v; };
union FragU8 { us8 u;    bf16x8 v; };

__device__ __forceinline__ void ins3(float& a, float& b, float& c, float v){
  if (v < c){
    c = v;
    if (c < b){ float t=b; b=c; c=t;
      if (b < a){ t=a; a=b; b=t; }
    }
  }
}

#define MFMA __builtin_amdgcn_mfma_f32_16x16x32_bf16

// ---------------------------------------------------------------------------
// Pass 1: fp32 [c][hw] -> bf16 TRANSPOSED [hw][c] + per-hw norm partials.
// (round-9 version: best measured total)
// ---------------------------------------------------------------------------
__global__ __launch_bounds__(256)
void convert_transpose(const float* __restrict__ S, const float* __restrict__ R,
                       unsigned short* __restrict__ tS, unsigned short* __restrict__ tR,
                       float* __restrict__ pnorm){
  const int blk = blockIdx.x;
  const int e   = blk >> 11;
  const int b   = (blk >> 7) & 15;
  const int hwT = (blk >> 3) & 15;
  const int cT  = blk & 7;
  const float* src = (e ? R : S) + (size_t)b*CDIM*HW;
  unsigned short* dst = (e ? tR : tS) + (size_t)b*HW*CDIM;

  const int t   = threadIdx.x;
  const int cj  = t & 15;
  const int hwg = t >> 4;
  const int hw0 = hwT*64 + hwg*4;
  const int c0  = cT*128 + cj*8;

  f4 col[8];
  #pragma unroll
  for (int i = 0; i < 8; ++i)
    col[i] = *(const f4*)&src[(size_t)(c0 + i)*HW + hw0];

  float sq0=0.f, sq1=0.f, sq2=0.f, sq3=0.f;
  #pragma unroll
  for (int j = 0; j < 4; ++j){
    us8 pk;
    float sq = 0.f;
    #pragma unroll
    for (int i = 0; i < 8; ++i){
      __hip_bfloat16 h = __float2bfloat16(col[i][j]);
      pk[i] = __builtin_bit_cast(unsigned short, h);
      const float g = __bfloat162float(h);
      sq = fmaf(g, g, sq);
    }
    *(us8*)&dst[(size_t)(hw0 + j)*CDIM + c0] = pk;
    if (j==0) sq0=sq; else if (j==1) sq1=sq; else if (j==2) sq2=sq; else sq3=sq;
  }
  #pragma unroll
  for (int m = 1; m < 16; m <<= 1){
    sq0 += __shfl_xor(sq0, m);
    sq1 += __shfl_xor(sq1, m);
    sq2 += __shfl_xor(sq2, m);
    sq3 += __shfl_xor(sq3, m);
  }
  if (cj == 0){
    f4 o = {sq0, sq1, sq2, sq3};
    *(f4*)&pnorm[((size_t)(e*16 + b)*8 + cT)*HW + hw0] = o;
  }
}

__global__ __launch_bounds__(256)
void norm_reduce(const float* __restrict__ pnorm, float* __restrict__ snorm){
  const int eb = blockIdx.x;
  const int t  = threadIdx.x;
  #pragma unroll
  for (int r = 0; r < 4; ++r){
    const int hw = r*256 + t;
    float a = 0.f;
    #pragma unroll
    for (int ct = 0; ct < 8; ++ct)
      a += pnorm[((size_t)eb*8 + ct)*HW + hw];
    snorm[(size_t)eb*HW + hw] = sqrtf(a);
  }
}

// ---------------------------------------------------------------------------
// Pass 2 (v7): v5's proven 256x256 / 8-wave / 3-buf data path, with each
// K-tile split into TWO setprio-wrapped phases (T3/T5): p0 = {stage A-pair
// (kt+2), counted vmcnt, barrier, read B0-3+A0-3, 16 MFMA}; p1 = {stage
// B-pair, read A4-7, 16 MFMA, barrier}.  vmcnt ledger: 2 loads/phase ->
// vmcnt(6) at p0 guarantees tile kt's data landed; tail 4 -> 0.
// ---------------------------------------------------------------------------
__global__ __launch_bounds__(512, 2)
void fused_gemm_top3_v7(const unsigned short* __restrict__ tS,
                        const unsigned short* __restrict__ tR,
                        const float* __restrict__ snorm,
                        const int*   __restrict__ anchor,
                        const int*   __restrict__ posidx,
                        float* __restrict__ wtop,   // [NTOT][NCHUNK][3]
                        float* __restrict__ wpos)   // [NTOT]
{
  __shared__ unsigned short stage[49152];   // 96KB: A 3x16KB, B 3x16KB
  __shared__ int   p_lds[256], q_lds[256];
  __shared__ float nAs[256], nBs[256];      // RECIPROCAL norms

  const int t = threadIdx.x;
  const uint32_t bid = blockIdx.x;
  const uint32_t L = (bid & 7u)*32u + (bid >> 3);   // XCD swizzle (256%8==0)
  const int b  = L >> 4;
  const int ni = (L >> 2) & 3;
  const int mi = L & 3;

  const unsigned short* SbT = tS + (size_t)b*HW*CDIM;
  const unsigned short* RbT = tR + (size_t)b*HW*CDIM;

  if (t < 256){
    const int n_g = ni*256 + t;
    const int* ap = anchor + (size_t)(b*NA + n_g)*3;
    const int* pp = posidx + (size_t)(b*NA + n_g)*3;
    const int pv = ap[2]*FWID + ap[1];
    p_lds[t] = pv;
    q_lds[t] = pp[2]*FWID + pp[1];
    nAs[t] = 1.0f / snorm[(size_t)b*HW + pv];
  } else {
    nBs[t-256] = 1.0f / snorm[(size_t)(BATCH + b)*HW + mi*256 + (t-256)];
  }
  __syncthreads();

  const int l  = t & 63;
  const int w  = t >> 6;
  const int wr = w >> 2, wc = w & 3;

  const int gkc = (l&3) ^ ((l>>3)&3);
  const int r0  = w*32 + (l>>2);
  const int r1  = r0 + 16;
  const unsigned short* gA0 = SbT + (size_t)p_lds[r0]*CDIM + gkc*8;
  const unsigned short* gA1 = SbT + (size_t)p_lds[r1]*CDIM + gkc*8;
  const unsigned short* gB0 = RbT + (size_t)(mi*256 + r0)*CDIM + gkc*8;
  const unsigned short* gB1 = RbT + (size_t)(mi*256 + r1)*CDIM + gkc*8;
  unsigned short* lA = &stage[w*1024];
  unsigned short* lB = &stage[24576 + w*1024];

  const int fbase = (l&15)*32 + (((l>>4) ^ ((l>>1)&3))*8);
  const int abase = wr*4096 + fbase;
  const int bbase = 24576 + wc*2048 + fbase;

  f32x4 acc[8][4];
  #pragma unroll
  for (int i=0;i<8;i++){
    #pragma unroll
    for (int j=0;j<4;j++){ f32x4 z = {0.f,0.f,0.f,0.f}; acc[i][j] = z; }
  }

  auto stageA = [&](int bo, int kt){
    const int ko = kt*32;
    gload16(gA0 + ko, lA + bo);
    gload16(gA1 + ko, lA + bo + 512);
  };
  auto stageB = [&](int bo, int kt){
    const int ko = kt*32;
    gload16(gB0 + ko, lB + bo);
    gload16(gB1 + ko, lB + bo + 512);
  };

  // ---- prologue: tiles 0 and 1 fully staged ----
  stageA(0, 0);     stageB(0, 0);
  stageA(8192, 1);  stageB(8192, 1);

  int oc = 0, on = 8192, on2 = 16384;
  for (int kt = 0; kt < 32; ++kt){
    // ======== phase 0 ========
    if (kt < 30) stageA(on2, kt+2);
    if (kt < 30)       { asm volatile("s_waitcnt vmcnt(6)" ::: "memory"); }
    else if (kt == 30) { asm volatile("s_waitcnt vmcnt(4)" ::: "memory"); }
    else               { asm volatile("s_waitcnt vmcnt(0)" ::: "memory"); }
    __builtin_amdgcn_s_barrier();

    FragU8 Bf0,Bf1,Bf2,Bf3, Af0,Af1,Af2,Af3;
    Bf0.u = *(const us8*)&stage[bbase + oc];
    Bf1.u = *(const us8*)&stage[bbase + oc + 512];
    Bf2.u = *(const us8*)&stage[bbase + oc + 1024];
    Bf3.u = *(const us8*)&stage[bbase + oc + 1536];
    Af0.u = *(const us8*)&stage[abase + oc];
    Af1.u = *(const us8*)&stage[abase + oc + 512];
    Af2.u = *(const us8*)&stage[abase + oc + 1024];
    Af3.u = *(const us8*)&stage[abase + oc + 1536];
    asm volatile("s_waitcnt lgkmcnt(0)" ::: "memory");
    __builtin_amdgcn_sched_barrier(0);
    __builtin_amdgcn_s_setprio(1);
    acc[0][0]=MFMA(Af0.v,Bf0.v,acc[0][0],0,0,0);
    acc[0][1]=MFMA(Af0.v,Bf1.v,acc[0][1],0,0,0);
    acc[0][2]=MFMA(Af0.v,Bf2.v,acc[0][2],0,0,0);
    acc[0][3]=MFMA(Af0.v,Bf3.v,acc[0][3],0,0,0);
    acc[1][0]=MFMA(Af1.v,Bf0.v,acc[1][0],0,0,0);
    acc[1][1]=MFMA(Af1.v,Bf1.v,acc[1][1],0,0,0);
    acc[1][2]=MFMA(Af1.v,Bf2.v,acc[1][2],0,0,0);
    acc[1][3]=MFMA(Af1.v,Bf3.v,acc[1][3],0,0,0);
    acc[2][0]=MFMA(Af2.v,Bf0.v,acc[2][0],0,0,0);
    acc[2][1]=MFMA(Af2.v,Bf1.v,acc[2][1],0,0,0);
    acc[2][2]=MFMA(Af2.v,Bf2.v,acc[2][2],0,0,0);
    acc[2][3]=MFMA(Af2.v,Bf3.v,acc[2][3],0,0,0);
    acc[3][0]=MFMA(Af3.v,Bf0.v,acc[3][0],0,0,0);
    acc[3][1]=MFMA(Af3.v,Bf1.v,acc[3][1],0,0,0);
    acc[3][2]=MFMA(Af3.v,Bf2.v,acc[3][2],0,0,0);
    acc[3][3]=MFMA(Af3.v,Bf3.v,acc[3][3],0,0,0);
    __builtin_amdgcn_s_setprio(0);

    // ======== phase 1 ========
    if (kt < 30) stageB(on2, kt+2);
    FragU8 Ag0,Ag1,Ag2,Ag3;
    Ag0.u = *(const us8*)&stage[abase + oc + 2048];
    Ag1.u = *(const us8*)&stage[abase + oc + 2560];
    Ag2.u = *(const us8*)&stage[abase + oc + 3072];
    Ag3.u = *(const us8*)&stage[abase + oc + 3584];
    asm volatile("s_waitcnt lgkmcnt(0)" ::: "memory");
    __builtin_amdgcn_sched_barrier(0);
    __builtin_amdgcn_s_setprio(1);
    acc[4][0]=MFMA(Ag0.v,Bf0.v,acc[4][0],0,0,0);
    acc[4][1]=MFMA(Ag0.v,Bf1.v,acc[4][1],0,0,0);
    acc[4][2]=MFMA(Ag0.v,Bf2.v,acc[4][2],0,0,0);
    acc[4][3]=MFMA(Ag0.v,Bf3.v,acc[4][3],0,0,0);
    acc[5][0]=MFMA(Ag1.v,Bf0.v,acc[5][0],0,0,0);
    acc[5][1]=MFMA(Ag1.v,Bf1.v,acc[5][1],0,0,0);
    acc[5][2]=MFMA(Ag1.v,Bf2.v,acc[5][2],0,0,0);
    acc[5][3]=MFMA(Ag1.v,Bf3.v,acc[5][3],0,0,0);
    acc[6][0]=MFMA(Ag2.v,Bf0.v,acc[6][0],0,0,0);
    acc[6][1]=MFMA(Ag2.v,Bf1.v,acc[6][1],0,0,0);
    acc[6][2]=MFMA(Ag2.v,Bf2.v,acc[6][2],0,0,0);
    acc[6][3]=MFMA(Ag2.v,Bf3.v,acc[6][3],0,0,0);
    acc[7][0]=MFMA(Ag3.v,Bf0.v,acc[7][0],0,0,0);
    acc[7][1]=MFMA(Ag3.v,Bf1.v,acc[7][1],0,0,0);
    acc[7][2]=MFMA(Ag3.v,Bf2.v,acc[7][2],0,0,0);
    acc[7][3]=MFMA(Ag3.v,Bf3.v,acc[7][3],0,0,0);
    __builtin_amdgcn_s_setprio(0);
    __builtin_amdgcn_s_barrier();   // end-of-tile: reads done before kt+1.p0 stages buf (kt)%3

    const int tmp = oc; oc = on; on = on2; on2 = tmp;
  }

  // ---- epilogue: reciprocal norms + LDS two-phase top3 (v5, proven) ----
  __syncthreads();
  float* tls = (float*)&stage[0] + (size_t)w*1152;

  float rinv[4];
  #pragma unroll
  for (int fb=0; fb<4; ++fb) rinv[fb] = nBs[wc*64 + fb*16 + (l&15)];

  #pragma unroll
  for (int fa=0; fa<8; ++fa){
    #pragma unroll
    for (int r=0; r<4; ++r){
      const int rg    = (l>>4)*4 + r;
      const int row_l = wr*128 + fa*16 + rg;
      const float ain = nAs[row_l];
      const float v0 = acc[fa][0][r] * ain * rinv[0];
      const float v1 = acc[fa][1][r] * ain * rinv[1];
      const float v2 = acc[fa][2][r] * ain * rinv[2];
      const float v3 = acc[fa][3][r] * ain * rinv[3];

      const int n_g = ni*256 + row_l;
      const int q   = q_lds[row_l];
      const int ql  = q - (mi*256 + wc*64);
      if (ql >= 0 && ql < 64 && (ql & 15) == (l & 15)){
        const int sel = ql >> 4;
        const float pv = sel==0 ? v0 : sel==1 ? v1 : sel==2 ? v2 : v3;
        wpos[b*NA + n_g] = pv;
      }

      float x=1e30f, y=1e30f, z=1e30f;
      ins3(x,y,z,v0); ins3(x,y,z,v1); ins3(x,y,z,v2); ins3(x,y,z,v3);
      f4 tr = {x, y, z, 0.f};
      *(f4*)(tls + (rg*17 + (l&15))*4) = tr;
    }
    asm volatile("s_waitcnt lgkmcnt(0)" ::: "memory");
    __builtin_amdgcn_sched_barrier(0);

    {
      const int rr = l >> 2;
      const float* rbp = tls + (rr*17 + (l&3)*4)*4;
      const f4 t0 = *(const f4*)(rbp);
      const f4 t1 = *(const f4*)(rbp + 4);
      const f4 t2 = *(const f4*)(rbp + 8);
      const f4 t3 = *(const f4*)(rbp + 12);
      float x = t0[0], y = t0[1], z = t0[2];
      ins3(x,y,z,t1[0]); ins3(x,y,z,t1[1]); ins3(x,y,z,t1[2]);
      ins3(x,y,z,t2[0]); ins3(x,y,z,t2[1]); ins3(x,y,z,t2[2]);
      ins3(x,y,z,t3[0]); ins3(x,y,z,t3[1]); ins3(x,y,z,t3[2]);
      #pragma unroll
      for (int m=1; m<4; m<<=1){
        const float ox = __shfl_xor(x, m);
        const float oy = __shfl_xor(y, m);
        const float oz = __shfl_xor(z, m);
        ins3(x,y,z,ox); ins3(x,y,z,oy); ins3(x,y,z,oz);
      }
      if ((l & 3) == 0){
        const int n_g = ni*256 + wr*128 + fa*16 + rr;
        float* dst = wtop + ((size_t)(b*NA + n_g)*NCHUNK + (mi*4 + wc))*3;
        dst[0]=x; dst[1]=y; dst[2]=z;
      }
    }
    asm volatile("s_waitcnt lgkmcnt(0)" ::: "memory");
    __builtin_amdgcn_sched_barrier(0);
  }
}

// ---------------------------------------------------------------------------
// v1 (verified) fused kernel — fallback when workspace is too small.
// ---------------------------------------------------------------------------
__global__ __launch_bounds__(256)
void fused_gemm_top3_v1(const float* __restrict__ sketch,
                        const float* __restrict__ refk,
                        const int*   __restrict__ anchor,
                        const int*   __restrict__ posidx,
                        float* __restrict__ wtop,
                        float* __restrict__ wpos)
{
  __shared__ union {
    unsigned short stage[16384];
    struct { float nA[16][128]; float nB[16][128]; } nrm;
  } sh;
  __shared__ int   p_lds[128];
  __shared__ float nA2[128], nB2[128];

  const int t = threadIdx.x;
  const uint32_t bid = blockIdx.x;
  const uint32_t L = (bid & 7u)*128u + (bid >> 3);
  const int b  = L >> 6;
  const int ni = (L >> 3) & 7;
  const int mi = L & 7;

  const float* Sb = sketch + (size_t)b*CDIM*HW;
  const float* Rb = refk   + (size_t)b*CDIM*HW;

  if (t < 128){
    const int n_g = ni*128 + t;
    const int* ap = anchor + (size_t)(b*NA + n_g)*3;
    p_lds[t] = ap[2]*FWID + ap[1];
  }
  __syncthreads();
  const int p0 = p_lds[0];
  int okf = 1;
  if (t < 128) okf = (p_lds[t] == p0 + t);
  const int contig = __syncthreads_and(okf);

  const int colg = (t & 15)*8;
  const int rowg = t >> 4;
  const int mbase = mi*128;

  const int l  = t & 63;
  const int w  = t >> 6;
  const int wr = w >> 1, wc = w & 1;
  const uint32_t sh_base = (uint32_t)(uintptr_t)&sh.stage[0];
  const uint32_t laneA = ((uint32_t)(l>>4))*2048u + (uint32_t)wr*512u + (uint32_t)(l&15)*8u;
  const uint32_t laneB = ((uint32_t)(l>>4))*2048u + (uint32_t)wc*512u + (uint32_t)(l&15)*8u;
  const int off0 = ((rowg>>2)*8 + (colg>>4))*64 + (rowg&3)*16 + (colg&15);

  f32x4 acc[4][4];
  #pragma unroll
  for (int i=0;i<4;i++){
    #pragma unroll
    for (int j=0;j<4;j++){ f32x4 z = {0.f,0.f,0.f,0.f}; acc[i][j] = z; }
  }

  float sqA[8] = {0,0,0,0,0,0,0,0};
  float sqB[8] = {0,0,0,0,0,0,0,0};
  f4 ra[4], rb[4];

  auto load_tile = [&](int kt){
    const int c0 = kt*32 + rowg;
    const float* SA = Sb + (size_t)c0*HW;
    const float* RB = Rb + (size_t)c0*HW + mbase + colg;
    if (contig){
      const float* pA = SA + p0 + colg;
      ra[0] = *(const f4*)(pA);
      ra[1] = *(const f4*)(pA + 4);
      ra[2] = *(const f4*)(pA + 16*HW);
      ra[3] = *(const f4*)(pA + 16*HW + 4);
    } else {
      float* raf = (float*)ra;
      #pragma unroll
      for (int i=0;i<8;i++){
        const int pc = p_lds[colg + i];
        raf[i]   = SA[pc];
        raf[8+i] = SA[16*HW + pc];
      }
    }
    rb[0] = *(const f4*)(RB);
    rb[1] = *(const f4*)(RB + 4);
    rb[2] = *(const f4*)(RB + 16*HW);
    rb[3] = *(const f4*)(RB + 16*HW + 4);
  };

  auto cvt_store = [&](int buf){
    const float* raf = (const float*)ra;
    const float* rbf = (const float*)rb;
    us8 pk;
    #pragma unroll
    for (int i=0;i<8;i++){
      __hip_bfloat16 h = __float2bfloat16(raf[i]);
      pk[i] = __builtin_bit_cast(unsigned short, h);
      const float g = __bfloat162float(h);
      sqA[i] = fmaf(g, g, sqA[i]);
    }
    *(us8*)&sh.stage[buf*4096 + off0] = pk;
    #pragma unroll
    for (int i=0;i<8;i++){
      __hip_bfloat16 h = __float2bfloat16(raf[8+i]);
      pk[i] = __builtin_bit_cast(unsigned short, h);
      const float g = __bfloat162float(h);
      sqA[i] = fmaf(g, g, sqA[i]);
    }
    *(us8*)&sh.stage[buf*4096 + off0 + 2048] = pk;
    #pragma unroll
    for (int i=0;i<8;i++){
      __hip_bfloat16 h = __float2bfloat16(rbf[i]);
      pk[i] = __builtin_bit_cast(unsigned short, h);
      const float g = __bfloat162float(h);
      sqB[i] = fmaf(g, g, sqB[i]);
    }
    *(us8*)&sh.stage[8192 + buf*4096 + off0] = pk;
    #pragma unroll
    for (int i=0;i<8;i++){
      __hip_bfloat16 h = __float2bfloat16(rbf[8+i]);
      pk[i] = __builtin_bit_cast(unsigned short, h);
      const float g = __bfloat162float(h);
      sqB[i] = fmaf(g, g, sqB[i]);
    }
    *(us8*)&sh.stage[8192 + buf*4096 + off0 + 2048] = pk;
  };

  auto compute = [&](int buf){
    const uint32_t aaddr = sh_base + (uint32_t)buf*8192u + laneA;
    const uint32_t baddr = sh_base + 16384u + (uint32_t)buf*8192u + laneB;
    FragU A0,A1,A2,A3,B0,B1,B2,B3;
    A0.h[0]=tr_read<0>(aaddr);    A0.h[1]=tr_read<1024>(aaddr);
    A1.h[0]=tr_read<128>(aaddr);  A1.h[1]=tr_read<1152>(aaddr);
    A2.h[0]=tr_read<256>(aaddr);  A2.h[1]=tr_read<1280>(aaddr);
    A3.h[0]=tr_read<384>(aaddr);  A3.h[1]=tr_read<1408>(aaddr);
    B0.h[0]=tr_read<0>(baddr);    B0.h[1]=tr_read<1024>(baddr);
    B1.h[0]=tr_read<128>(baddr);  B1.h[1]=tr_read<1152>(baddr);
    B2.h[0]=tr_read<256>(baddr);  B2.h[1]=tr_read<1280>(baddr);
    B3.h[0]=tr_read<384>(baddr);  B3.h[1]=tr_read<1408>(baddr);
    asm volatile("s_waitcnt lgkmcnt(0)" ::: "memory");
    __builtin_amdgcn_sched_barrier(0);
    acc[0][0]=MFMA(A0.v,B0.v,acc[0][0],0,0,0);
    acc[0][1]=MFMA(A0.v,B1.v,acc[0][1],0,0,0);
    acc[0][2]=MFMA(A0.v,B2.v,acc[0][2],0,0,0);
    acc[0][3]=MFMA(A0.v,B3.v,acc[0][3],0,0,0);
    acc[1][0]=MFMA(A1.v,B0.v,acc[1][0],0,0,0);
    acc[1][1]=MFMA(A1.v,B1.v,acc[1][1],0,0,0);
    acc[1][2]=MFMA(A1.v,B2.v,acc[1][2],0,0,0);
    acc[1][3]=MFMA(A1.v,B3.v,acc[1][3],0,0,0);
    acc[2][0]=MFMA(A2.v,B0.v,acc[2][0],0,0,0);
    acc[2][1]=MFMA(A2.v,B1.v,acc[2][1],0,0,0);
    acc[2][2]=MFMA(A2.v,B2.v,acc[2][2],0,0,0);
    acc[2][3]=MFMA(A2.v,B3.v,acc[2][3],0,0,0);
    acc[3][0]=MFMA(A3.v,B0.v,acc[3][0],0,0,0);
    acc[3][1]=MFMA(A3.v,B1.v,acc[3][1],0,0,0);
    acc[3][2]=MFMA(A3.v,B2.v,acc[3][2],0,0,0);
    acc[3][3]=MFMA(A3.v,B3.v,acc[3][3],0,0,0);
  };

  load_tile(0);
  cvt_store(0);
  __syncthreads();
  int buf = 0;
  for (int kt = 0; kt < 32; ++kt){
    if (kt < 31) load_tile(kt+1);
    compute(buf);
    if (kt < 31) cvt_store(buf^1);
    __syncthreads();
    buf ^= 1;
  }

  #pragma unroll
  for (int i=0;i<8;i++) sh.nrm.nA[rowg][colg+i] = sqA[i];
  #pragma unroll
  for (int i=0;i<8;i++) sh.nrm.nB[rowg][colg+i] = sqB[i];
  __syncthreads();
  if (t < 128){
    float s = 0.f;
    #pragma unroll
    for (int r=0;r<16;r++) s += sh.nrm.nA[r][t];
    nA2[t] = s;
  } else {
    const int c2 = t - 128;
    float s = 0.f;
    #pragma unroll
    for (int r=0;r<16;r++) s += sh.nrm.nB[r][c2];
    nB2[c2] = s;
  }
  __syncthreads();

  float rncol[4];
  #pragma unroll
  for (int nf=0;nf<4;nf++) rncol[nf] = sqrtf(nB2[wc*64 + nf*16 + (l&15)]);

  #pragma unroll
  for (int mf=0; mf<4; ++mf){
    #pragma unroll
    for (int r=0; r<4; ++r){
      const int row_l = wr*64 + mf*16 + (l>>4)*4 + r;
      const int n_g   = ni*128 + row_l;
      const float an  = sqrtf(nA2[row_l]);
      const float v0 = acc[mf][0][r] / fmaxf(an*rncol[0], 1e-8f);
      const float v1 = acc[mf][1][r] / fmaxf(an*rncol[1], 1e-8f);
      const float v2 = acc[mf][2][r] / fmaxf(an*rncol[2], 1e-8f);
      const float v3 = acc[mf][3][r] / fmaxf(an*rncol[3], 1e-8f);

      const int* pp = posidx + (size_t)(b*NA + n_g)*3;
      const int q  = pp[2]*FWID + pp[1];
      const int ql = q - (mbase + wc*64);
      if (ql >= 0 && ql < 64 && (ql & 15) == (l & 15)){
        const int sel = ql >> 4;
        const float pv = sel==0 ? v0 : sel==1 ? v1 : sel==2 ? v2 : v3;
        wpos[b*NA + n_g] = pv;
      }

      float x=1e30f, y=1e30f, z=1e30f;
      ins3(x,y,z,v0); ins3(x,y,z,v1); ins3(x,y,z,v2); ins3(x,y,z,v3);
      #pragma unroll
      for (int m=1; m<16; m<<=1){
        const float ox = __shfl_xor(x, m);
        const float oy = __shfl_xor(y, m);
        const float oz = __shfl_xor(z, m);
        ins3(x,y,z,ox); ins3(x,y,z,oy); ins3(x,y,z,oz);
      }
      if ((l & 15) == 0){
        float* dst = wtop + ((size_t)(b*NA + n_g)*NCHUNK + (mi*2 + wc))*3;
        dst[0]=x; dst[1]=y; dst[2]=z;
      }
    }
  }
}

// ---------------------------------------------------------------------------
__global__ __launch_bounds__(256)
void merge_top3(const float* __restrict__ wtop, const float* __restrict__ wpos,
                float* __restrict__ partial){
  __shared__ float red[256];
  const int id = blockIdx.x*256 + threadIdx.x;
  const float* src = wtop + (size_t)id*(NCHUNK*3);
  float x=1e30f, y=1e30f, z=1e30f;
  #pragma unroll
  for (int i=0;i<NCHUNK*3;i++) ins3(x,y,z, src[i]);
  const float loss = fmaxf((x+y+z) - wpos[id] + MARGIN, 0.0f);
  red[threadIdx.x] = loss;
  __syncthreads();
  for (int s=128; s>0; s>>=1){
    if (threadIdx.x < s) red[threadIdx.x] += red[threadIdx.x+s];
    __syncthreads();
  }
  if (threadIdx.x == 0) partial[blockIdx.x] = red[0];
}

__global__ void final_sum(const float* __restrict__ partial, float* __restrict__ out){
  float v = partial[threadIdx.x];
  #pragma unroll
  for (int off=32; off>0; off>>=1) v += __shfl_down(v, off);
  if (threadIdx.x == 0) out[0] = v / (1e-6f + (float)NTOT);
}

// ---------------------------------------------------------------------------
extern "C" void kernel_launch(void* const* d_in, const int* in_sizes, int n_in,
                              void* d_out, int out_size, void* d_ws, size_t ws_size,
                              hipStream_t stream){
  const float* sketch = (const float*)d_in[0];
  const float* refk   = (const float*)d_in[1];
  const int*   anchor = (const int*)d_in[2];
  const int*   posidx = (const int*)d_in[3];
  float* out = (float*)d_out;

  float* wtop    = (float*)d_ws;                       // NTOT*NCHUNK*3 floats
  float* wpos    = wtop + (size_t)NTOT*NCHUNK*3;       // NTOT floats
  float* partial = wpos + NTOT;                        // 64 floats (+pad)
  unsigned short* tS = (unsigned short*)(partial + 256);
  unsigned short* tR = tS + (size_t)BATCH*HW*CDIM;
  float* pnorm = (float*)(tR + (size_t)BATCH*HW*CDIM); // 32*8*1024 floats
  float* snorm = pnorm + (size_t)32*8*1024;            // 32*1024 floats
  const size_t need = (size_t)((char*)(snorm + 32*1024) - (char*)d_ws);

  if (ws_size >= need){
    convert_transpose<<<dim3(4096), dim3(256), 0, stream>>>(sketch, refk, tS, tR, pnorm);
    norm_reduce<<<dim3(32), dim3(256), 0, stream>>>(pnorm, snorm);
    fused_gemm_top3_v7<<<dim3(256), dim3(512), 0, stream>>>(tS, tR, snorm, anchor, posidx, wtop, wpos);
  } else {
    fused_gemm_top3_v1<<<dim3(1024), dim3(256), 0, stream>>>(sketch, refk, anchor, posidx, wtop, wpos);
  }
  merge_top3<<<dim3(64), dim3(256), 0, stream>>>(wtop, wpos, partial);
  final_sum<<<dim3(1), dim3(64), 0, stream>>>(partial, out);
}

// Round 12
// 99.378 us; speedup vs baseline: 1.1448x; 1.0230x over previous
//
#include <hip/hip_runtime.h>
#include <hip/hip_bf16.h>
#include <stdint.h>

// ---------------- problem constants ----------------
#define BATCH 16
#define CDIM  1024
#define FWID  32
#define HW    1024
#define NA    1024
#define NTOT  (BATCH*NA)    // 16384
#define NCHUNK 16           // 4 mi-tiles * 4 wc waves = 16 chunks of 64 cols
#define MARGIN 0.6f

typedef __bf16 bf16x8 __attribute__((ext_vector_type(8)));
typedef float  f32x4  __attribute__((ext_vector_type(4)));
typedef unsigned short us4 __attribute__((ext_vector_type(4)));
typedef unsigned short us8 __attribute__((ext_vector_type(8)));
typedef float  f4     __attribute__((ext_vector_type(4)));

template<int OFF>
__device__ __forceinline__ us4 tr_read(uint32_t addr){
  us4 r;
  asm volatile("ds_read_b64_tr_b16 %0, %1 offset:%2" : "=v"(r) : "v"(addr), "n"(OFF));
  return r;
}

__device__ __forceinline__ void gload16(const unsigned short* g, unsigned short* l){
  __builtin_amdgcn_global_load_lds((const __attribute__((address_space(1))) void*)g,
                                   (__attribute__((address_space(3))) void*)l, 16, 0, 0);
}

union FragU  { us4 h[2]; bf16x8 v; };
union FragU8 { us8 u;    bf16x8 v; };

__device__ __forceinline__ void ins3(float& a, float& b, float& c, float v){
  if (v < c){
    c = v;
    if (c < b){ float t=b; b=c; c=t;
      if (b < a){ t=a; a=b; b=t; }
    }
  }
}

#define MFMA __builtin_amdgcn_mfma_f32_16x16x32_bf16

// ---------------------------------------------------------------------------
// Pass 1: fp32 [c][hw] -> bf16 TRANSPOSED [hw][c] + per-hw norm partials.
// ---------------------------------------------------------------------------
__global__ __launch_bounds__(256)
void convert_transpose(const float* __restrict__ S, const float* __restrict__ R,
                       unsigned short* __restrict__ tS, unsigned short* __restrict__ tR,
                       float* __restrict__ pnorm){
  const int blk = blockIdx.x;
  const int e   = blk >> 11;
  const int b   = (blk >> 7) & 15;
  const int hwT = (blk >> 3) & 15;
  const int cT  = blk & 7;
  const float* src = (e ? R : S) + (size_t)b*CDIM*HW;
  unsigned short* dst = (e ? tR : tS) + (size_t)b*HW*CDIM;

  const int t   = threadIdx.x;
  const int cj  = t & 15;
  const int hwg = t >> 4;
  const int hw0 = hwT*64 + hwg*4;
  const int c0  = cT*128 + cj*8;

  f4 col[8];
  #pragma unroll
  for (int i = 0; i < 8; ++i)
    col[i] = *(const f4*)&src[(size_t)(c0 + i)*HW + hw0];

  float sq0=0.f, sq1=0.f, sq2=0.f, sq3=0.f;
  #pragma unroll
  for (int j = 0; j < 4; ++j){
    us8 pk;
    float sq = 0.f;
    #pragma unroll
    for (int i = 0; i < 8; ++i){
      __hip_bfloat16 h = __float2bfloat16(col[i][j]);
      pk[i] = __builtin_bit_cast(unsigned short, h);
      const float g = __bfloat162float(h);
      sq = fmaf(g, g, sq);
    }
    *(us8*)&dst[(size_t)(hw0 + j)*CDIM + c0] = pk;
    if (j==0) sq0=sq; else if (j==1) sq1=sq; else if (j==2) sq2=sq; else sq3=sq;
  }
  #pragma unroll
  for (int m = 1; m < 16; m <<= 1){
    sq0 += __shfl_xor(sq0, m);
    sq1 += __shfl_xor(sq1, m);
    sq2 += __shfl_xor(sq2, m);
    sq3 += __shfl_xor(sq3, m);
  }
  if (cj == 0){
    f4 o = {sq0, sq1, sq2, sq3};
    *(f4*)&pnorm[((size_t)(e*16 + b)*8 + cT)*HW + hw0] = o;
  }
}

__global__ __launch_bounds__(256)
void norm_reduce(const float* __restrict__ pnorm, float* __restrict__ snorm){
  const int eb = blockIdx.x;
  const int t  = threadIdx.x;
  #pragma unroll
  for (int r = 0; r < 4; ++r){
    const int hw = r*256 + t;
    float a = 0.f;
    #pragma unroll
    for (int ct = 0; ct < 8; ++ct)
      a += pnorm[((size_t)eb*8 + ct)*HW + hw];
    snorm[(size_t)eb*HW + hw] = sqrtf(a);
  }
}

// ---------------------------------------------------------------------------
// Pass 2 (v8): v7's data path + one-phase READ-AHEAD pipeline.
// Per tile kt: P0 = {stage4(kt+2); issue Ahi(kt); MFMA-lo (B+Alo issued last
// phase)}; P1 = {lgkm(0); vmcnt; barrier; issue B+Alo(kt+1); MFMA-hi}.
// lgkm(0) BEFORE the barrier makes the buf-overwrite WAR airtight.
// Reg ping-pong via unroll-2 with named sets (no runtime indexing).
// ---------------------------------------------------------------------------
__global__ __launch_bounds__(512, 2)
void fused_gemm_top3_v8(const unsigned short* __restrict__ tS,
                        const unsigned short* __restrict__ tR,
                        const float* __restrict__ snorm,
                        const int*   __restrict__ anchor,
                        const int*   __restrict__ posidx,
                        float* __restrict__ wtop,   // [NTOT][NCHUNK][3]
                        float* __restrict__ wpos)   // [NTOT]
{
  __shared__ unsigned short stage[49152];   // 96KB: A 3x16KB, B 3x16KB
  __shared__ int   p_lds[256], q_lds[256];
  __shared__ float nAs[256], nBs[256];      // RECIPROCAL norms

  const int t = threadIdx.x;
  const uint32_t bid = blockIdx.x;
  const uint32_t L = (bid & 7u)*32u + (bid >> 3);   // XCD swizzle (256%8==0)
  const int b  = L >> 4;
  const int ni = (L >> 2) & 3;
  const int mi = L & 3;

  const unsigned short* SbT = tS + (size_t)b*HW*CDIM;
  const unsigned short* RbT = tR + (size_t)b*HW*CDIM;

  if (t < 256){
    const int n_g = ni*256 + t;
    const int* ap = anchor + (size_t)(b*NA + n_g)*3;
    const int* pp = posidx + (size_t)(b*NA + n_g)*3;
    const int pv = ap[2]*FWID + ap[1];
    p_lds[t] = pv;
    q_lds[t] = pp[2]*FWID + pp[1];
    nAs[t] = 1.0f / snorm[(size_t)b*HW + pv];
  } else {
    nBs[t-256] = 1.0f / snorm[(size_t)(BATCH + b)*HW + mi*256 + (t-256)];
  }
  __syncthreads();

  const int l  = t & 63;
  const int w  = t >> 6;
  const int wr = w >> 2, wc = w & 3;

  const int gkc = (l&3) ^ ((l>>3)&3);
  const int r0  = w*32 + (l>>2);
  const int r1  = r0 + 16;
  const unsigned short* gA0 = SbT + (size_t)p_lds[r0]*CDIM + gkc*8;
  const unsigned short* gA1 = SbT + (size_t)p_lds[r1]*CDIM + gkc*8;
  const unsigned short* gB0 = RbT + (size_t)(mi*256 + r0)*CDIM + gkc*8;
  const unsigned short* gB1 = RbT + (size_t)(mi*256 + r1)*CDIM + gkc*8;
  unsigned short* lA = &stage[w*1024];
  unsigned short* lB = &stage[24576 + w*1024];

  const int fbase = (l&15)*32 + (((l>>4) ^ ((l>>1)&3))*8);
  const int abase = wr*4096 + fbase;
  const int bbase = 24576 + wc*2048 + fbase;

  f32x4 acc[8][4];
  #pragma unroll
  for (int i=0;i<8;i++){
    #pragma unroll
    for (int j=0;j<4;j++){ f32x4 z = {0.f,0.f,0.f,0.f}; acc[i][j] = z; }
  }

  auto stage4 = [&](int bo, int kt){
    const int ko = kt*32;
    gload16(gA0 + ko, lA + bo);
    gload16(gA1 + ko, lA + bo + 512);
    gload16(gB0 + ko, lB + bo);
    gload16(gB1 + ko, lB + bo + 512);
  };

  FragU8 Bc0,Bc1,Bc2,Bc3, Bn0,Bn1,Bn2,Bn3;
  FragU8 Ac0,Ac1,Ac2,Ac3, An0,An1,An2,An3;
  FragU8 Ah0,Ah1,Ah2,Ah3;

#define RD(dst, off) (dst).u = *(const us8*)&stage[(off)]

  auto mfma_lo = [&](FragU8& A0, FragU8& A1, FragU8& A2, FragU8& A3,
                     FragU8& B0, FragU8& B1, FragU8& B2, FragU8& B3){
    acc[0][0]=MFMA(A0.v,B0.v,acc[0][0],0,0,0);
    acc[0][1]=MFMA(A0.v,B1.v,acc[0][1],0,0,0);
    acc[0][2]=MFMA(A0.v,B2.v,acc[0][2],0,0,0);
    acc[0][3]=MFMA(A0.v,B3.v,acc[0][3],0,0,0);
    acc[1][0]=MFMA(A1.v,B0.v,acc[1][0],0,0,0);
    acc[1][1]=MFMA(A1.v,B1.v,acc[1][1],0,0,0);
    acc[1][2]=MFMA(A1.v,B2.v,acc[1][2],0,0,0);
    acc[1][3]=MFMA(A1.v,B3.v,acc[1][3],0,0,0);
    acc[2][0]=MFMA(A2.v,B0.v,acc[2][0],0,0,0);
    acc[2][1]=MFMA(A2.v,B1.v,acc[2][1],0,0,0);
    acc[2][2]=MFMA(A2.v,B2.v,acc[2][2],0,0,0);
    acc[2][3]=MFMA(A2.v,B3.v,acc[2][3],0,0,0);
    acc[3][0]=MFMA(A3.v,B0.v,acc[3][0],0,0,0);
    acc[3][1]=MFMA(A3.v,B1.v,acc[3][1],0,0,0);
    acc[3][2]=MFMA(A3.v,B2.v,acc[3][2],0,0,0);
    acc[3][3]=MFMA(A3.v,B3.v,acc[3][3],0,0,0);
  };
  auto mfma_hi = [&](FragU8& B0, FragU8& B1, FragU8& B2, FragU8& B3){
    acc[4][0]=MFMA(Ah0.v,B0.v,acc[4][0],0,0,0);
    acc[4][1]=MFMA(Ah0.v,B1.v,acc[4][1],0,0,0);
    acc[4][2]=MFMA(Ah0.v,B2.v,acc[4][2],0,0,0);
    acc[4][3]=MFMA(Ah0.v,B3.v,acc[4][3],0,0,0);
    acc[5][0]=MFMA(Ah1.v,B0.v,acc[5][0],0,0,0);
    acc[5][1]=MFMA(Ah1.v,B1.v,acc[5][1],0,0,0);
    acc[5][2]=MFMA(Ah1.v,B2.v,acc[5][2],0,0,0);
    acc[5][3]=MFMA(Ah1.v,B3.v,acc[5][3],0,0,0);
    acc[6][0]=MFMA(Ah2.v,B0.v,acc[6][0],0,0,0);
    acc[6][1]=MFMA(Ah2.v,B1.v,acc[6][1],0,0,0);
    acc[6][2]=MFMA(Ah2.v,B2.v,acc[6][2],0,0,0);
    acc[6][3]=MFMA(Ah2.v,B3.v,acc[6][3],0,0,0);
    acc[7][0]=MFMA(Ah3.v,B0.v,acc[7][0],0,0,0);
    acc[7][1]=MFMA(Ah3.v,B1.v,acc[7][1],0,0,0);
    acc[7][2]=MFMA(Ah3.v,B2.v,acc[7][2],0,0,0);
    acc[7][3]=MFMA(Ah3.v,B3.v,acc[7][3],0,0,0);
  };

#define RD_AHI(OC) \
  RD(Ah0, abase + (OC) + 2048); RD(Ah1, abase + (OC) + 2560); \
  RD(Ah2, abase + (OC) + 3072); RD(Ah3, abase + (OC) + 3584)

#define RD_SET(B0,B1,B2,B3,A0,A1,A2,A3, OFF) \
  RD(B0, bbase + (OFF));        RD(B1, bbase + (OFF) + 512); \
  RD(B2, bbase + (OFF) + 1024); RD(B3, bbase + (OFF) + 1536); \
  RD(A0, abase + (OFF));        RD(A1, abase + (OFF) + 512); \
  RD(A2, abase + (OFF) + 1024); RD(A3, abase + (OFF) + 1536)

  // ---- prologue ----
  stage4(0, 0);
  stage4(8192, 1);
  asm volatile("s_waitcnt vmcnt(4)" ::: "memory");   // tile 0 landed
  __builtin_amdgcn_s_barrier();
  __builtin_amdgcn_sched_barrier(0);
  RD_SET(Bc0,Bc1,Bc2,Bc3, Ac0,Ac1,Ac2,Ac3, 0);      // tile 0 lo-set

  int oc = 0, on = 8192, on2 = 16384;
  for (int kt2 = 0; kt2 < 15; ++kt2){
    const int kt = 2*kt2;
    // ======== tile kt (even, current = c-set) ========
    stage4(on2, kt+2);
    RD_AHI(oc);
    __builtin_amdgcn_sched_barrier(0);
    __builtin_amdgcn_s_setprio(1);
    mfma_lo(Ac0,Ac1,Ac2,Ac3, Bc0,Bc1,Bc2,Bc3);
    __builtin_amdgcn_s_setprio(0);
    asm volatile("s_waitcnt lgkmcnt(0)" ::: "memory");   // drain Ahi -> WAR airtight
    asm volatile("s_waitcnt vmcnt(4)" ::: "memory");     // tile kt+1 landed
    __builtin_amdgcn_s_barrier();
    __builtin_amdgcn_sched_barrier(0);
    RD_SET(Bn0,Bn1,Bn2,Bn3, An0,An1,An2,An3, on);        // tile kt+1 lo-set
    __builtin_amdgcn_sched_barrier(0);
    __builtin_amdgcn_s_setprio(1);
    mfma_hi(Bc0,Bc1,Bc2,Bc3);
    __builtin_amdgcn_s_setprio(0);
    { const int tmp = oc; oc = on; on = on2; on2 = tmp; }

    // ======== tile kt+1 (odd, current = n-set) ========
    stage4(on2, kt+3);
    RD_AHI(oc);
    __builtin_amdgcn_sched_barrier(0);
    __builtin_amdgcn_s_setprio(1);
    mfma_lo(An0,An1,An2,An3, Bn0,Bn1,Bn2,Bn3);
    __builtin_amdgcn_s_setprio(0);
    asm volatile("s_waitcnt lgkmcnt(0)" ::: "memory");
    asm volatile("s_waitcnt vmcnt(4)" ::: "memory");     // tile kt+2 landed
    __builtin_amdgcn_s_barrier();
    __builtin_amdgcn_sched_barrier(0);
    RD_SET(Bc0,Bc1,Bc2,Bc3, Ac0,Ac1,Ac2,Ac3, on);        // tile kt+2 lo-set
    __builtin_amdgcn_sched_barrier(0);
    __builtin_amdgcn_s_setprio(1);
    mfma_hi(Bn0,Bn1,Bn2,Bn3);
    __builtin_amdgcn_s_setprio(0);
    { const int tmp = oc; oc = on; on = on2; on2 = tmp; }
  }

  // ======== tile 30 (even, c-set) ========
  RD_AHI(oc);
  __builtin_amdgcn_sched_barrier(0);
  __builtin_amdgcn_s_setprio(1);
  mfma_lo(Ac0,Ac1,Ac2,Ac3, Bc0,Bc1,Bc2,Bc3);
  __builtin_amdgcn_s_setprio(0);
  asm volatile("s_waitcnt lgkmcnt(0)" ::: "memory");
  asm volatile("s_waitcnt vmcnt(0)" ::: "memory");       // tile 31 landed
  __builtin_amdgcn_s_barrier();
  __builtin_amdgcn_sched_barrier(0);
  RD_SET(Bn0,Bn1,Bn2,Bn3, An0,An1,An2,An3, on);          // tile 31 lo-set
  __builtin_amdgcn_sched_barrier(0);
  __builtin_amdgcn_s_setprio(1);
  mfma_hi(Bc0,Bc1,Bc2,Bc3);
  __builtin_amdgcn_s_setprio(0);
  { const int tmp = oc; oc = on; on = on2; on2 = tmp; }

  // ======== tile 31 (odd, n-set) ========
  RD_AHI(oc);
  __builtin_amdgcn_sched_barrier(0);
  __builtin_amdgcn_s_setprio(1);
  mfma_lo(An0,An1,An2,An3, Bn0,Bn1,Bn2,Bn3);
  __builtin_amdgcn_s_setprio(0);
  asm volatile("s_waitcnt lgkmcnt(0)" ::: "memory");
  __builtin_amdgcn_s_setprio(1);
  mfma_hi(Bn0,Bn1,Bn2,Bn3);
  __builtin_amdgcn_s_setprio(0);

#undef RD
#undef RD_AHI
#undef RD_SET

  // ---- epilogue: reciprocal norms + LDS two-phase top3 (proven) ----
  __syncthreads();
  float* tls = (float*)&stage[0] + (size_t)w*1152;

  float rinv[4];
  #pragma unroll
  for (int fb=0; fb<4; ++fb) rinv[fb] = nBs[wc*64 + fb*16 + (l&15)];

  #pragma unroll
  for (int fa=0; fa<8; ++fa){
    #pragma unroll
    for (int r=0; r<4; ++r){
      const int rg    = (l>>4)*4 + r;
      const int row_l = wr*128 + fa*16 + rg;
      const float ain = nAs[row_l];
      const float v0 = acc[fa][0][r] * ain * rinv[0];
      const float v1 = acc[fa][1][r] * ain * rinv[1];
      const float v2 = acc[fa][2][r] * ain * rinv[2];
      const float v3 = acc[fa][3][r] * ain * rinv[3];

      const int n_g = ni*256 + row_l;
      const int q   = q_lds[row_l];
      const int ql  = q - (mi*256 + wc*64);
      if (ql >= 0 && ql < 64 && (ql & 15) == (l & 15)){
        const int sel = ql >> 4;
        const float pv = sel==0 ? v0 : sel==1 ? v1 : sel==2 ? v2 : v3;
        wpos[b*NA + n_g] = pv;
      }

      float x=1e30f, y=1e30f, z=1e30f;
      ins3(x,y,z,v0); ins3(x,y,z,v1); ins3(x,y,z,v2); ins3(x,y,z,v3);
      f4 tr = {x, y, z, 0.f};
      *(f4*)(tls + (rg*17 + (l&15))*4) = tr;
    }
    asm volatile("s_waitcnt lgkmcnt(0)" ::: "memory");
    __builtin_amdgcn_sched_barrier(0);

    {
      const int rr = l >> 2;
      const float* rbp = tls + (rr*17 + (l&3)*4)*4;
      const f4 t0 = *(const f4*)(rbp);
      const f4 t1 = *(const f4*)(rbp + 4);
      const f4 t2 = *(const f4*)(rbp + 8);
      const f4 t3 = *(const f4*)(rbp + 12);
      float x = t0[0], y = t0[1], z = t0[2];
      ins3(x,y,z,t1[0]); ins3(x,y,z,t1[1]); ins3(x,y,z,t1[2]);
      ins3(x,y,z,t2[0]); ins3(x,y,z,t2[1]); ins3(x,y,z,t2[2]);
      ins3(x,y,z,t3[0]); ins3(x,y,z,t3[1]); ins3(x,y,z,t3[2]);
      #pragma unroll
      for (int m=1; m<4; m<<=1){
        const float ox = __shfl_xor(x, m);
        const float oy = __shfl_xor(y, m);
        const float oz = __shfl_xor(z, m);
        ins3(x,y,z,ox); ins3(x,y,z,oy); ins3(x,y,z,oz);
      }
      if ((l & 3) == 0){
        const int n_g = ni*256 + wr*128 + fa*16 + rr;
        float* dst = wtop + ((size_t)(b*NA + n_g)*NCHUNK + (mi*4 + wc))*3;
        dst[0]=x; dst[1]=y; dst[2]=z;
      }
    }
    asm volatile("s_waitcnt lgkmcnt(0)" ::: "memory");
    __builtin_amdgcn_sched_barrier(0);
  }
}

// ---------------------------------------------------------------------------
// v1 (verified) fused kernel — fallback when workspace is too small.
// ---------------------------------------------------------------------------
__global__ __launch_bounds__(256)
void fused_gemm_top3_v1(const float* __restrict__ sketch,
                        const float* __restrict__ refk,
                        const int*   __restrict__ anchor,
                        const int*   __restrict__ posidx,
                        float* __restrict__ wtop,
                        float* __restrict__ wpos)
{
  __shared__ union {
    unsigned short stage[16384];
    struct { float nA[16][128]; float nB[16][128]; } nrm;
  } sh;
  __shared__ int   p_lds[128];
  __shared__ float nA2[128], nB2[128];

  const int t = threadIdx.x;
  const uint32_t bid = blockIdx.x;
  const uint32_t L = (bid & 7u)*128u + (bid >> 3);
  const int b  = L >> 6;
  const int ni = (L >> 3) & 7;
  const int mi = L & 7;

  const float* Sb = sketch + (size_t)b*CDIM*HW;
  const float* Rb = refk   + (size_t)b*CDIM*HW;

  if (t < 128){
    const int n_g = ni*128 + t;
    const int* ap = anchor + (size_t)(b*NA + n_g)*3;
    p_lds[t] = ap[2]*FWID + ap[1];
  }
  __syncthreads();
  const int p0 = p_lds[0];
  int okf = 1;
  if (t < 128) okf = (p_lds[t] == p0 + t);
  const int contig = __syncthreads_and(okf);

  const int colg = (t & 15)*8;
  const int rowg = t >> 4;
  const int mbase = mi*128;

  const int l  = t & 63;
  const int w  = t >> 6;
  const int wr = w >> 1, wc = w & 1;
  const uint32_t sh_base = (uint32_t)(uintptr_t)&sh.stage[0];
  const uint32_t laneA = ((uint32_t)(l>>4))*2048u + (uint32_t)wr*512u + (uint32_t)(l&15)*8u;
  const uint32_t laneB = ((uint32_t)(l>>4))*2048u + (uint32_t)wc*512u + (uint32_t)(l&15)*8u;
  const int off0 = ((rowg>>2)*8 + (colg>>4))*64 + (rowg&3)*16 + (colg&15);

  f32x4 acc[4][4];
  #pragma unroll
  for (int i=0;i<4;i++){
    #pragma unroll
    for (int j=0;j<4;j++){ f32x4 z = {0.f,0.f,0.f,0.f}; acc[i][j] = z; }
  }

  float sqA[8] = {0,0,0,0,0,0,0,0};
  float sqB[8] = {0,0,0,0,0,0,0,0};
  f4 ra[4], rb[4];

  auto load_tile = [&](int kt){
    const int c0 = kt*32 + rowg;
    const float* SA = Sb + (size_t)c0*HW;
    const float* RB = Rb + (size_t)c0*HW + mbase + colg;
    if (contig){
      const float* pA = SA + p0 + colg;
      ra[0] = *(const f4*)(pA);
      ra[1] = *(const f4*)(pA + 4);
      ra[2] = *(const f4*)(pA + 16*HW);
      ra[3] = *(const f4*)(pA + 16*HW + 4);
    } else {
      float* raf = (float*)ra;
      #pragma unroll
      for (int i=0;i<8;i++){
        const int pc = p_lds[colg + i];
        raf[i]   = SA[pc];
        raf[8+i] = SA[16*HW + pc];
      }
    }
    rb[0] = *(const f4*)(RB);
    rb[1] = *(const f4*)(RB + 4);
    rb[2] = *(const f4*)(RB + 16*HW);
    rb[3] = *(const f4*)(RB + 16*HW + 4);
  };

  auto cvt_store = [&](int buf){
    const float* raf = (const float*)ra;
    const float* rbf = (const float*)rb;
    us8 pk;
    #pragma unroll
    for (int i=0;i<8;i++){
      __hip_bfloat16 h = __float2bfloat16(raf[i]);
      pk[i] = __builtin_bit_cast(unsigned short, h);
      const float g = __bfloat162float(h);
      sqA[i] = fmaf(g, g, sqA[i]);
    }
    *(us8*)&sh.stage[buf*4096 + off0] = pk;
    #pragma unroll
    for (int i=0;i<8;i++){
      __hip_bfloat16 h = __float2bfloat16(raf[8+i]);
      pk[i] = __builtin_bit_cast(unsigned short, h);
      const float g = __bfloat162float(h);
      sqA[i] = fmaf(g, g, sqA[i]);
    }
    *(us8*)&sh.stage[buf*4096 + off0 + 2048] = pk;
    #pragma unroll
    for (int i=0;i<8;i++){
      __hip_bfloat16 h = __float2bfloat16(rbf[i]);
      pk[i] = __builtin_bit_cast(unsigned short, h);
      const float g = __bfloat162float(h);
      sqB[i] = fmaf(g, g, sqB[i]);
    }
    *(us8*)&sh.stage[8192 + buf*4096 + off0] = pk;
    #pragma unroll
    for (int i=0;i<8;i++){
      __hip_bfloat16 h = __float2bfloat16(rbf[8+i]);
      pk[i] = __builtin_bit_cast(unsigned short, h);
      const float g = __bfloat162float(h);
      sqB[i] = fmaf(g, g, sqB[i]);
    }
    *(us8*)&sh.stage[8192 + buf*4096 + off0 + 2048] = pk;
  };

  auto compute = [&](int buf){
    const uint32_t aaddr = sh_base + (uint32_t)buf*8192u + laneA;
    const uint32_t baddr = sh_base + 16384u + (uint32_t)buf*8192u + laneB;
    FragU A0,A1,A2,A3,B0,B1,B2,B3;
    A0.h[0]=tr_read<0>(aaddr);    A0.h[1]=tr_read<1024>(aaddr);
    A1.h[0]=tr_read<128>(aaddr);  A1.h[1]=tr_read<1152>(aaddr);
    A2.h[0]=tr_read<256>(aaddr);  A2.h[1]=tr_read<1280>(aaddr);
    A3.h[0]=tr_read<384>(aaddr);  A3.h[1]=tr_read<1408>(aaddr);
    B0.h[0]=tr_read<0>(baddr);    B0.h[1]=tr_read<1024>(baddr);
    B1.h[0]=tr_read<128>(baddr);  B1.h[1]=tr_read<1152>(baddr);
    B2.h[0]=tr_read<256>(baddr);  B2.h[1]=tr_read<1280>(baddr);
    B3.h[0]=tr_read<384>(baddr);  B3.h[1]=tr_read<1408>(baddr);
    asm volatile("s_waitcnt lgkmcnt(0)" ::: "memory");
    __builtin_amdgcn_sched_barrier(0);
    acc[0][0]=MFMA(A0.v,B0.v,acc[0][0],0,0,0);
    acc[0][1]=MFMA(A0.v,B1.v,acc[0][1],0,0,0);
    acc[0][2]=MFMA(A0.v,B2.v,acc[0][2],0,0,0);
    acc[0][3]=MFMA(A0.v,B3.v,acc[0][3],0,0,0);
    acc[1][0]=MFMA(A1.v,B0.v,acc[1][0],0,0,0);
    acc[1][1]=MFMA(A1.v,B1.v,acc[1][1],0,0,0);
    acc[1][2]=MFMA(A1.v,B2.v,acc[1][2],0,0,0);
    acc[1][3]=MFMA(A1.v,B3.v,acc[1][3],0,0,0);
    acc[2][0]=MFMA(A2.v,B0.v,acc[2][0],0,0,0);
    acc[2][1]=MFMA(A2.v,B1.v,acc[2][1],0,0,0);
    acc[2][2]=MFMA(A2.v,B2.v,acc[2][2],0,0,0);
    acc[2][3]=MFMA(A2.v,B3.v,acc[2][3],0,0,0);
    acc[3][0]=MFMA(A3.v,B0.v,acc[3][0],0,0,0);
    acc[3][1]=MFMA(A3.v,B1.v,acc[3][1],0,0,0);
    acc[3][2]=MFMA(A3.v,B2.v,acc[3][2],0,0,0);
    acc[3][3]=MFMA(A3.v,B3.v,acc[3][3],0,0,0);
  };

  load_tile(0);
  cvt_store(0);
  __syncthreads();
  int buf = 0;
  for (int kt = 0; kt < 32; ++kt){
    if (kt < 31) load_tile(kt+1);
    compute(buf);
    if (kt < 31) cvt_store(buf^1);
    __syncthreads();
    buf ^= 1;
  }

  #pragma unroll
  for (int i=0;i<8;i++) sh.nrm.nA[rowg][colg+i] = sqA[i];
  #pragma unroll
  for (int i=0;i<8;i++) sh.nrm.nB[rowg][colg+i] = sqB[i];
  __syncthreads();
  if (t < 128){
    float s = 0.f;
    #pragma unroll
    for (int r=0;r<16;r++) s += sh.nrm.nA[r][t];
    nA2[t] = s;
  } else {
    const int c2 = t - 128;
    float s = 0.f;
    #pragma unroll
    for (int r=0;r<16;r++) s += sh.nrm.nB[r][c2];
    nB2[c2] = s;
  }
  __syncthreads();

  float rncol[4];
  #pragma unroll
  for (int nf=0;nf<4;nf++) rncol[nf] = sqrtf(nB2[wc*64 + nf*16 + (l&15)]);

  #pragma unroll
  for (int mf=0; mf<4; ++mf){
    #pragma unroll
    for (int r=0; r<4; ++r){
      const int row_l = wr*64 + mf*16 + (l>>4)*4 + r;
      const int n_g   = ni*128 + row_l;
      const float an  = sqrtf(nA2[row_l]);
      const float v0 = acc[mf][0][r] / fmaxf(an*rncol[0], 1e-8f);
      const float v1 = acc[mf][1][r] / fmaxf(an*rncol[1], 1e-8f);
      const float v2 = acc[mf][2][r] / fmaxf(an*rncol[2], 1e-8f);
      const float v3 = acc[mf][3][r] / fmaxf(an*rncol[3], 1e-8f);

      const int* pp = posidx + (size_t)(b*NA + n_g)*3;
      const int q  = pp[2]*FWID + pp[1];
      const int ql = q - (mbase + wc*64);
      if (ql >= 0 && ql < 64 && (ql & 15) == (l & 15)){
        const int sel = ql >> 4;
        const float pv = sel==0 ? v0 : sel==1 ? v1 : sel==2 ? v2 : v3;
        wpos[b*NA + n_g] = pv;
      }

      float x=1e30f, y=1e30f, z=1e30f;
      ins3(x,y,z,v0); ins3(x,y,z,v1); ins3(x,y,z,v2); ins3(x,y,z,v3);
      #pragma unroll
      for (int m=1; m<16; m<<=1){
        const float ox = __shfl_xor(x, m);
        const float oy = __shfl_xor(y, m);
        const float oz = __shfl_xor(z, m);
        ins3(x,y,z,ox); ins3(x,y,z,oy); ins3(x,y,z,oz);
      }
      if ((l & 15) == 0){
        float* dst = wtop + ((size_t)(b*NA + n_g)*NCHUNK + (mi*2 + wc))*3;
        dst[0]=x; dst[1]=y; dst[2]=z;
      }
    }
  }
}

// ---------------------------------------------------------------------------
__global__ __launch_bounds__(256)
void merge_top3(const float* __restrict__ wtop, const float* __restrict__ wpos,
                float* __restrict__ partial){
  __shared__ float red[256];
  const int id = blockIdx.x*256 + threadIdx.x;
  const float* src = wtop + (size_t)id*(NCHUNK*3);
  float x=1e30f, y=1e30f, z=1e30f;
  #pragma unroll
  for (int i=0;i<NCHUNK*3;i++) ins3(x,y,z, src[i]);
  const float loss = fmaxf((x+y+z) - wpos[id] + MARGIN, 0.0f);
  red[threadIdx.x] = loss;
  __syncthreads();
  for (int s=128; s>0; s>>=1){
    if (threadIdx.x < s) red[threadIdx.x] += red[threadIdx.x+s];
    __syncthreads();
  }
  if (threadIdx.x == 0) partial[blockIdx.x] = red[0];
}

__global__ void final_sum(const float* __restrict__ partial, float* __restrict__ out){
  float v = partial[threadIdx.x];
  #pragma unroll
  for (int off=32; off>0; off>>=1) v += __shfl_down(v, off);
  if (threadIdx.x == 0) out[0] = v / (1e-6f + (float)NTOT);
}

// ---------------------------------------------------------------------------
extern "C" void kernel_launch(void* const* d_in, const int* in_sizes, int n_in,
                              void* d_out, int out_size, void* d_ws, size_t ws_size,
                              hipStream_t stream){
  const float* sketch = (const float*)d_in[0];
  const float* refk   = (const float*)d_in[1];
  const int*   anchor = (const int*)d_in[2];
  const int*   posidx = (const int*)d_in[3];
  float* out = (float*)d_out;

  float* wtop    = (float*)d_ws;                       // NTOT*NCHUNK*3 floats
  float* wpos    = wtop + (size_t)NTOT*NCHUNK*3;       // NTOT floats
  float* partial = wpos + NTOT;                        // 64 floats (+pad)
  unsigned short* tS = (unsigned short*)(partial + 256);
  unsigned short* tR = tS + (size_t)BATCH*HW*CDIM;
  float* pnorm = (float*)(tR + (size_t)BATCH*HW*CDIM); // 32*8*1024 floats
  float* snorm = pnorm + (size_t)32*8*1024;            // 32*1024 floats
  const size_t need = (size_t)((char*)(snorm + 32*1024) - (char*)d_ws);

  if (ws_size >= need){
    convert_transpose<<<dim3(4096), dim3(256), 0, stream>>>(sketch, refk, tS, tR, pnorm);
    norm_reduce<<<dim3(32), dim3(256), 0, stream>>>(pnorm, snorm);
    fused_gemm_top3_v8<<<dim3(256), dim3(512), 0, stream>>>(tS, tR, snorm, anchor, posidx, wtop, wpos);
  } else {
    fused_gemm_top3_v1<<<dim3(1024), dim3(256), 0, stream>>>(sketch, refk, anchor, posidx, wtop, wpos);
  }
  merge_top3<<<dim3(64), dim3(256), 0, stream>>>(wtop, wpos, partial);
  final_sum<<<dim3(1), dim3(64), 0, stream>>>(partial, out);
}

// Round 13
// 97.249 us; speedup vs baseline: 1.1699x; 1.0219x over previous
//
#include <hip/hip_runtime.h>
#include <hip/hip_bf16.h>
#include <stdint.h>

// ---------------- problem constants ----------------
#define BATCH 16
#define CDIM  1024
#define FWID  32
#define HW    1024
#define NA    1024
#define NTOT  (BATCH*NA)    // 16384
#define NCHUNK 16           // 4 mi-tiles * 4 wc waves = 16 chunks of 64 cols
#define MARGIN 0.6f

typedef __bf16 bf16x8 __attribute__((ext_vector_type(8)));
typedef float  f32x4  __attribute__((ext_vector_type(4)));
typedef unsigned short us4 __attribute__((ext_vector_type(4)));
typedef unsigned short us8 __attribute__((ext_vector_type(8)));
typedef float  f4     __attribute__((ext_vector_type(4)));

template<int OFF>
__device__ __forceinline__ us4 tr_read(uint32_t addr){
  us4 r;
  asm volatile("ds_read_b64_tr_b16 %0, %1 offset:%2" : "=v"(r) : "v"(addr), "n"(OFF));
  return r;
}

__device__ __forceinline__ void gload16(const unsigned short* g, unsigned short* l){
  __builtin_amdgcn_global_load_lds((const __attribute__((address_space(1))) void*)g,
                                   (__attribute__((address_space(3))) void*)l, 16, 0, 0);
}

union FragU  { us4 h[2]; bf16x8 v; };
union FragU8 { us8 u;    bf16x8 v; };

__device__ __forceinline__ void ins3(float& a, float& b, float& c, float v){
  if (v < c){
    c = v;
    if (c < b){ float t=b; b=c; c=t;
      if (b < a){ t=a; a=b; b=t; }
    }
  }
}

#define MFMA __builtin_amdgcn_mfma_f32_16x16x32_bf16

// ---------------------------------------------------------------------------
// Pass 1 (v3): fp32 [c][hw] -> bf16 [hw][c], 2x-deep loads (16 f4 in flight
// per thread) to attack the latency/request-rate bound.  grid 2048 =
// e(2) x b(16) x hwT(16) x cP(4); each block: 64 hw x 256 c.
// ---------------------------------------------------------------------------
__global__ __launch_bounds__(256)
void convert_transpose3(const float* __restrict__ S, const float* __restrict__ R,
                        unsigned short* __restrict__ tS, unsigned short* __restrict__ tR,
                        float* __restrict__ pnorm){
  const int blk = blockIdx.x;
  const int e   = blk >> 10;
  const int b   = (blk >> 6) & 15;
  const int hwT = (blk >> 2) & 15;
  const int cP  = blk & 3;
  const float* src = (e ? R : S) + (size_t)b*CDIM*HW;
  unsigned short* dst = (e ? tR : tS) + (size_t)b*HW*CDIM;

  const int t   = threadIdx.x;
  const int cj  = t & 15;
  const int hwg = t >> 4;
  const int hw0 = hwT*64 + hwg*4;
  const int cA  = cP*256 + cj*8;
  const int cB  = cA + 128;

  f4 colA[8], colB[8];
  #pragma unroll
  for (int i = 0; i < 8; ++i)
    colA[i] = *(const f4*)&src[(size_t)(cA + i)*HW + hw0];
  #pragma unroll
  for (int i = 0; i < 8; ++i)
    colB[i] = *(const f4*)&src[(size_t)(cB + i)*HW + hw0];

  float sqa[4] = {0.f,0.f,0.f,0.f};
  float sqb[4] = {0.f,0.f,0.f,0.f};
  #pragma unroll
  for (int j = 0; j < 4; ++j){
    us8 pk;
    float sq = 0.f;
    #pragma unroll
    for (int i = 0; i < 8; ++i){
      __hip_bfloat16 h = __float2bfloat16(colA[i][j]);
      pk[i] = __builtin_bit_cast(unsigned short, h);
      const float g = __bfloat162float(h);
      sq = fmaf(g, g, sq);
    }
    *(us8*)&dst[(size_t)(hw0 + j)*CDIM + cA] = pk;
    sqa[j] = sq;
  }
  #pragma unroll
  for (int j = 0; j < 4; ++j){
    us8 pk;
    float sq = 0.f;
    #pragma unroll
    for (int i = 0; i < 8; ++i){
      __hip_bfloat16 h = __float2bfloat16(colB[i][j]);
      pk[i] = __builtin_bit_cast(unsigned short, h);
      const float g = __bfloat162float(h);
      sq = fmaf(g, g, sq);
    }
    *(us8*)&dst[(size_t)(hw0 + j)*CDIM + cB] = pk;
    sqb[j] = sq;
  }
  #pragma unroll
  for (int m = 1; m < 16; m <<= 1){
    #pragma unroll
    for (int j = 0; j < 4; ++j){
      sqa[j] += __shfl_xor(sqa[j], m);
      sqb[j] += __shfl_xor(sqb[j], m);
    }
  }
  if (cj == 0){
    f4 oa = {sqa[0], sqa[1], sqa[2], sqa[3]};
    f4 ob = {sqb[0], sqb[1], sqb[2], sqb[3]};
    *(f4*)&pnorm[((size_t)(e*16 + b)*8 + cP*2    )*HW + hw0] = oa;
    *(f4*)&pnorm[((size_t)(e*16 + b)*8 + cP*2 + 1)*HW + hw0] = ob;
  }
}

__global__ __launch_bounds__(256)
void norm_reduce(const float* __restrict__ pnorm, float* __restrict__ snorm){
  const int eb = blockIdx.x;
  const int t  = threadIdx.x;
  #pragma unroll
  for (int r = 0; r < 4; ++r){
    const int hw = r*256 + t;
    float a = 0.f;
    #pragma unroll
    for (int ct = 0; ct < 8; ++ct)
      a += pnorm[((size_t)eb*8 + ct)*HW + hw];
    snorm[(size_t)eb*HW + hw] = sqrtf(a);
  }
}

// ---------------------------------------------------------------------------
// Pass 2 (v9): 256x256 / 8-wave, BK=64, 2 bufs (128 KB), ONE barrier per
// 64-K tile (16 total vs v8's 33).  Per tile: {vmcnt(0) on aged loads;
// barrier; stage8(kt+1); 2 x (12 ds_read_b128 + 32 MFMA)}.
// 8-chunk XOR swizzle: slot s of row R holds global chunk s^(R&7); each
// staged row is a CONTIGUOUS 128B global segment (2x v8's 64B).
// ---------------------------------------------------------------------------
__global__ __launch_bounds__(512, 2)
void fused_gemm_top3_v9(const unsigned short* __restrict__ tS,
                        const unsigned short* __restrict__ tR,
                        const float* __restrict__ snorm,
                        const int*   __restrict__ anchor,
                        const int*   __restrict__ posidx,
                        float* __restrict__ wtop,   // [NTOT][NCHUNK][3]
                        float* __restrict__ wpos)   // [NTOT]
{
  // A: us [0, 32768) = 2 bufs x 16384 us (32KB: 256 rows x 64 k);
  // B: us [32768, 65536).  Total 128 KB + 4 KB aux.
  __shared__ unsigned short stage[65536];
  __shared__ int   p_lds[256], q_lds[256];
  __shared__ float nAs[256], nBs[256];      // RECIPROCAL norms

  const int t = threadIdx.x;
  const uint32_t bid = blockIdx.x;
  const uint32_t L = (bid & 7u)*32u + (bid >> 3);   // XCD swizzle (256%8==0)
  const int b  = L >> 4;
  const int ni = (L >> 2) & 3;
  const int mi = L & 3;

  const unsigned short* SbT = tS + (size_t)b*HW*CDIM;
  const unsigned short* RbT = tR + (size_t)b*HW*CDIM;

  if (t < 256){
    const int n_g = ni*256 + t;
    const int* ap = anchor + (size_t)(b*NA + n_g)*3;
    const int* pp = posidx + (size_t)(b*NA + n_g)*3;
    const int pv = ap[2]*FWID + ap[1];
    p_lds[t] = pv;
    q_lds[t] = pp[2]*FWID + pp[1];
    nAs[t] = 1.0f / snorm[(size_t)b*HW + pv];
  } else {
    nBs[t-256] = 1.0f / snorm[(size_t)(BATCH + b)*HW + mi*256 + (t-256)];
  }
  __syncthreads();

  const int l  = t & 63;
  const int w  = t >> 6;
  const int wr = w >> 2, wc = w & 3;

  // ---- staging: per inst, 8 rows x 8 chunks; lane l -> row grp (l>>3),
  // stored slot (l&7); pre-swizzled global chunk gkc = (l&7) ^ ((l>>3)&7).
  const int gkc = (l&7) ^ ((l>>3)&7);
  const unsigned short* gA[4];
  const unsigned short* gB[4];
  #pragma unroll
  for (int i = 0; i < 4; ++i){
    const int row = w*32 + i*8 + (l>>3);
    gA[i] = SbT + (size_t)p_lds[row]*CDIM + gkc*8;
    gB[i] = RbT + (size_t)(mi*256 + row)*CDIM + gkc*8;
  }
  unsigned short* lA = &stage[w*2048];
  unsigned short* lB = &stage[32768 + w*2048];

  // ---- frag read bases (us): row*64 + slot*16B; slot = (kc+4h)^(l&7)
  const int fb0 = (l&15)*64 + (((l>>4)    ) ^ (l&7))*8;
  const int fb1 = (l&15)*64 + (((l>>4) + 4) ^ (l&7))*8;
  const int abase = wr*8192;            // wr*128 rows * 64 us
  const int bbase = 32768 + wc*4096;    // wc*64 rows * 64 us

  f32x4 acc[8][4];
  #pragma unroll
  for (int i=0;i<8;i++){
    #pragma unroll
    for (int j=0;j<4;j++){ f32x4 z = {0.f,0.f,0.f,0.f}; acc[i][j] = z; }
  }

  auto stage8 = [&](int bo, int kt){
    const int ko = kt*64;   // 128 B per row per tile
    #pragma unroll
    for (int i = 0; i < 4; ++i){
      gload16(gA[i] + ko, lA + bo + i*512);
      gload16(gB[i] + ko, lB + bo + i*512);
    }
  };

  auto half = [&](int bo, int fbh){
    FragU8 Bf[4], Af[8];
    #pragma unroll
    for (int fb=0; fb<4; ++fb) Bf[fb].u = *(const us8*)&stage[bbase + bo + fb*1024 + fbh];
    #pragma unroll
    for (int fa=0; fa<8; ++fa) Af[fa].u = *(const us8*)&stage[abase + bo + fa*1024 + fbh];
    __builtin_amdgcn_s_setprio(1);
    #pragma unroll
    for (int fa=0; fa<8; ++fa){
      #pragma unroll
      for (int fb=0; fb<4; ++fb)
        acc[fa][fb] = MFMA(Af[fa].v, Bf[fb].v, acc[fa][fb], 0,0,0);
    }
    __builtin_amdgcn_s_setprio(0);
  };

  // ---- main K loop: 16 tiles of BK=64, 2 bufs, 1 barrier/tile ----
  stage8(0, 0);
  int bo = 0;
  for (int kt = 0; kt < 16; ++kt){
    asm volatile("s_waitcnt vmcnt(0)" ::: "memory");  // tile kt landed (aged 1 full tile)
    __builtin_amdgcn_s_barrier();
    __builtin_amdgcn_sched_barrier(0);
    if (kt < 15) stage8(bo ^ 16384, kt+1);
    half(bo, fb0);
    half(bo, fb1);
    bo ^= 16384;
  }

  // ---- epilogue: reciprocal norms + LDS two-phase top3 (proven) ----
  __syncthreads();
  float* tls = (float*)&stage[0] + (size_t)w*1152;

  float rinv[4];
  #pragma unroll
  for (int fb=0; fb<4; ++fb) rinv[fb] = nBs[wc*64 + fb*16 + (l&15)];

  #pragma unroll
  for (int fa=0; fa<8; ++fa){
    #pragma unroll
    for (int r=0; r<4; ++r){
      const int rg    = (l>>4)*4 + r;
      const int row_l = wr*128 + fa*16 + rg;
      const float ain = nAs[row_l];
      const float v0 = acc[fa][0][r] * ain * rinv[0];
      const float v1 = acc[fa][1][r] * ain * rinv[1];
      const float v2 = acc[fa][2][r] * ain * rinv[2];
      const float v3 = acc[fa][3][r] * ain * rinv[3];

      const int n_g = ni*256 + row_l;
      const int q   = q_lds[row_l];
      const int ql  = q - (mi*256 + wc*64);
      if (ql >= 0 && ql < 64 && (ql & 15) == (l & 15)){
        const int sel = ql >> 4;
        const float pv = sel==0 ? v0 : sel==1 ? v1 : sel==2 ? v2 : v3;
        wpos[b*NA + n_g] = pv;
      }

      float x=1e30f, y=1e30f, z=1e30f;
      ins3(x,y,z,v0); ins3(x,y,z,v1); ins3(x,y,z,v2); ins3(x,y,z,v3);
      f4 tr = {x, y, z, 0.f};
      *(f4*)(tls + (rg*17 + (l&15))*4) = tr;
    }
    asm volatile("s_waitcnt lgkmcnt(0)" ::: "memory");
    __builtin_amdgcn_sched_barrier(0);

    {
      const int rr = l >> 2;
      const float* rbp = tls + (rr*17 + (l&3)*4)*4;
      const f4 t0 = *(const f4*)(rbp);
      const f4 t1 = *(const f4*)(rbp + 4);
      const f4 t2 = *(const f4*)(rbp + 8);
      const f4 t3 = *(const f4*)(rbp + 12);
      float x = t0[0], y = t0[1], z = t0[2];
      ins3(x,y,z,t1[0]); ins3(x,y,z,t1[1]); ins3(x,y,z,t1[2]);
      ins3(x,y,z,t2[0]); ins3(x,y,z,t2[1]); ins3(x,y,z,t2[2]);
      ins3(x,y,z,t3[0]); ins3(x,y,z,t3[1]); ins3(x,y,z,t3[2]);
      #pragma unroll
      for (int m=1; m<4; m<<=1){
        const float ox = __shfl_xor(x, m);
        const float oy = __shfl_xor(y, m);
        const float oz = __shfl_xor(z, m);
        ins3(x,y,z,ox); ins3(x,y,z,oy); ins3(x,y,z,oz);
      }
      if ((l & 3) == 0){
        const int n_g = ni*256 + wr*128 + fa*16 + rr;
        float* dst = wtop + ((size_t)(b*NA + n_g)*NCHUNK + (mi*4 + wc))*3;
        dst[0]=x; dst[1]=y; dst[2]=z;
      }
    }
    asm volatile("s_waitcnt lgkmcnt(0)" ::: "memory");
    __builtin_amdgcn_sched_barrier(0);
  }
}

// ---------------------------------------------------------------------------
// v1 (verified) fused kernel — fallback when workspace is too small.
// ---------------------------------------------------------------------------
__global__ __launch_bounds__(256)
void fused_gemm_top3_v1(const float* __restrict__ sketch,
                        const float* __restrict__ refk,
                        const int*   __restrict__ anchor,
                        const int*   __restrict__ posidx,
                        float* __restrict__ wtop,
                        float* __restrict__ wpos)
{
  __shared__ union {
    unsigned short stage[16384];
    struct { float nA[16][128]; float nB[16][128]; } nrm;
  } sh;
  __shared__ int   p_lds[128];
  __shared__ float nA2[128], nB2[128];

  const int t = threadIdx.x;
  const uint32_t bid = blockIdx.x;
  const uint32_t L = (bid & 7u)*128u + (bid >> 3);
  const int b  = L >> 6;
  const int ni = (L >> 3) & 7;
  const int mi = L & 7;

  const float* Sb = sketch + (size_t)b*CDIM*HW;
  const float* Rb = refk   + (size_t)b*CDIM*HW;

  if (t < 128){
    const int n_g = ni*128 + t;
    const int* ap = anchor + (size_t)(b*NA + n_g)*3;
    p_lds[t] = ap[2]*FWID + ap[1];
  }
  __syncthreads();
  const int p0 = p_lds[0];
  int okf = 1;
  if (t < 128) okf = (p_lds[t] == p0 + t);
  const int contig = __syncthreads_and(okf);

  const int colg = (t & 15)*8;
  const int rowg = t >> 4;
  const int mbase = mi*128;

  const int l  = t & 63;
  const int w  = t >> 6;
  const int wr = w >> 1, wc = w & 1;
  const uint32_t sh_base = (uint32_t)(uintptr_t)&sh.stage[0];
  const uint32_t laneA = ((uint32_t)(l>>4))*2048u + (uint32_t)wr*512u + (uint32_t)(l&15)*8u;
  const uint32_t laneB = ((uint32_t)(l>>4))*2048u + (uint32_t)wc*512u + (uint32_t)(l&15)*8u;
  const int off0 = ((rowg>>2)*8 + (colg>>4))*64 + (rowg&3)*16 + (colg&15);

  f32x4 acc[4][4];
  #pragma unroll
  for (int i=0;i<4;i++){
    #pragma unroll
    for (int j=0;j<4;j++){ f32x4 z = {0.f,0.f,0.f,0.f}; acc[i][j] = z; }
  }

  float sqA[8] = {0,0,0,0,0,0,0,0};
  float sqB[8] = {0,0,0,0,0,0,0,0};
  f4 ra[4], rb[4];

  auto load_tile = [&](int kt){
    const int c0 = kt*32 + rowg;
    const float* SA = Sb + (size_t)c0*HW;
    const float* RB = Rb + (size_t)c0*HW + mbase + colg;
    if (contig){
      const float* pA = SA + p0 + colg;
      ra[0] = *(const f4*)(pA);
      ra[1] = *(const f4*)(pA + 4);
      ra[2] = *(const f4*)(pA + 16*HW);
      ra[3] = *(const f4*)(pA + 16*HW + 4);
    } else {
      float* raf = (float*)ra;
      #pragma unroll
      for (int i=0;i<8;i++){
        const int pc = p_lds[colg + i];
        raf[i]   = SA[pc];
        raf[8+i] = SA[16*HW + pc];
      }
    }
    rb[0] = *(const f4*)(RB);
    rb[1] = *(const f4*)(RB + 4);
    rb[2] = *(const f4*)(RB + 16*HW);
    rb[3] = *(const f4*)(RB + 16*HW + 4);
  };

  auto cvt_store = [&](int buf){
    const float* raf = (const float*)ra;
    const float* rbf = (const float*)rb;
    us8 pk;
    #pragma unroll
    for (int i=0;i<8;i++){
      __hip_bfloat16 h = __float2bfloat16(raf[i]);
      pk[i] = __builtin_bit_cast(unsigned short, h);
      const float g = __bfloat162float(h);
      sqA[i] = fmaf(g, g, sqA[i]);
    }
    *(us8*)&sh.stage[buf*4096 + off0] = pk;
    #pragma unroll
    for (int i=0;i<8;i++){
      __hip_bfloat16 h = __float2bfloat16(raf[8+i]);
      pk[i] = __builtin_bit_cast(unsigned short, h);
      const float g = __bfloat162float(h);
      sqA[i] = fmaf(g, g, sqA[i]);
    }
    *(us8*)&sh.stage[buf*4096 + off0 + 2048] = pk;
    #pragma unroll
    for (int i=0;i<8;i++){
      __hip_bfloat16 h = __float2bfloat16(rbf[i]);
      pk[i] = __builtin_bit_cast(unsigned short, h);
      const float g = __bfloat162float(h);
      sqB[i] = fmaf(g, g, sqB[i]);
    }
    *(us8*)&sh.stage[8192 + buf*4096 + off0] = pk;
    #pragma unroll
    for (int i=0;i<8;i++){
      __hip_bfloat16 h = __float2bfloat16(rbf[8+i]);
      pk[i] = __builtin_bit_cast(unsigned short, h);
      const float g = __bfloat162float(h);
      sqB[i] = fmaf(g, g, sqB[i]);
    }
    *(us8*)&sh.stage[8192 + buf*4096 + off0 + 2048] = pk;
  };

  auto compute = [&](int buf){
    const uint32_t aaddr = sh_base + (uint32_t)buf*8192u + laneA;
    const uint32_t baddr = sh_base + 16384u + (uint32_t)buf*8192u + laneB;
    FragU A0,A1,A2,A3,B0,B1,B2,B3;
    A0.h[0]=tr_read<0>(aaddr);    A0.h[1]=tr_read<1024>(aaddr);
    A1.h[0]=tr_read<128>(aaddr);  A1.h[1]=tr_read<1152>(aaddr);
    A2.h[0]=tr_read<256>(aaddr);  A2.h[1]=tr_read<1280>(aaddr);
    A3.h[0]=tr_read<384>(aaddr);  A3.h[1]=tr_read<1408>(aaddr);
    B0.h[0]=tr_read<0>(baddr);    B0.h[1]=tr_read<1024>(baddr);
    B1.h[0]=tr_read<128>(baddr);  B1.h[1]=tr_read<1152>(baddr);
    B2.h[0]=tr_read<256>(baddr);  B2.h[1]=tr_read<1280>(baddr);
    B3.h[0]=tr_read<384>(baddr);  B3.h[1]=tr_read<1408>(baddr);
    asm volatile("s_waitcnt lgkmcnt(0)" ::: "memory");
    __builtin_amdgcn_sched_barrier(0);
    acc[0][0]=MFMA(A0.v,B0.v,acc[0][0],0,0,0);
    acc[0][1]=MFMA(A0.v,B1.v,acc[0][1],0,0,0);
    acc[0][2]=MFMA(A0.v,B2.v,acc[0][2],0,0,0);
    acc[0][3]=MFMA(A0.v,B3.v,acc[0][3],0,0,0);
    acc[1][0]=MFMA(A1.v,B0.v,acc[1][0],0,0,0);
    acc[1][1]=MFMA(A1.v,B1.v,acc[1][1],0,0,0);
    acc[1][2]=MFMA(A1.v,B2.v,acc[1][2],0,0,0);
    acc[1][3]=MFMA(A1.v,B3.v,acc[1][3],0,0,0);
    acc[2][0]=MFMA(A2.v,B0.v,acc[2][0],0,0,0);
    acc[2][1]=MFMA(A2.v,B1.v,acc[2][1],0,0,0);
    acc[2][2]=MFMA(A2.v,B2.v,acc[2][2],0,0,0);
    acc[2][3]=MFMA(A2.v,B3.v,acc[2][3],0,0,0);
    acc[3][0]=MFMA(A3.v,B0.v,acc[3][0],0,0,0);
    acc[3][1]=MFMA(A3.v,B1.v,acc[3][1],0,0,0);
    acc[3][2]=MFMA(A3.v,B2.v,acc[3][2],0,0,0);
    acc[3][3]=MFMA(A3.v,B3.v,acc[3][3],0,0,0);
  };

  load_tile(0);
  cvt_store(0);
  __syncthreads();
  int buf = 0;
  for (int kt = 0; kt < 32; ++kt){
    if (kt < 31) load_tile(kt+1);
    compute(buf);
    if (kt < 31) cvt_store(buf^1);
    __syncthreads();
    buf ^= 1;
  }

  #pragma unroll
  for (int i=0;i<8;i++) sh.nrm.nA[rowg][colg+i] = sqA[i];
  #pragma unroll
  for (int i=0;i<8;i++) sh.nrm.nB[rowg][colg+i] = sqB[i];
  __syncthreads();
  if (t < 128){
    float s = 0.f;
    #pragma unroll
    for (int r=0;r<16;r++) s += sh.nrm.nA[r][t];
    nA2[t] = s;
  } else {
    const int c2 = t - 128;
    float s = 0.f;
    #pragma unroll
    for (int r=0;r<16;r++) s += sh.nrm.nB[r][c2];
    nB2[c2] = s;
  }
  __syncthreads();

  float rncol[4];
  #pragma unroll
  for (int nf=0;nf<4;nf++) rncol[nf] = sqrtf(nB2[wc*64 + nf*16 + (l&15)]);

  #pragma unroll
  for (int mf=0; mf<4; ++mf){
    #pragma unroll
    for (int r=0; r<4; ++r){
      const int row_l = wr*64 + mf*16 + (l>>4)*4 + r;
      const int n_g   = ni*128 + row_l;
      const float an  = sqrtf(nA2[row_l]);
      const float v0 = acc[mf][0][r] / fmaxf(an*rncol[0], 1e-8f);
      const float v1 = acc[mf][1][r] / fmaxf(an*rncol[1], 1e-8f);
      const float v2 = acc[mf][2][r] / fmaxf(an*rncol[2], 1e-8f);
      const float v3 = acc[mf][3][r] / fmaxf(an*rncol[3], 1e-8f);

      const int* pp = posidx + (size_t)(b*NA + n_g)*3;
      const int q  = pp[2]*FWID + pp[1];
      const int ql = q - (mbase + wc*64);
      if (ql >= 0 && ql < 64 && (ql & 15) == (l & 15)){
        const int sel = ql >> 4;
        const float pv = sel==0 ? v0 : sel==1 ? v1 : sel==2 ? v2 : v3;
        wpos[b*NA + n_g] = pv;
      }

      float x=1e30f, y=1e30f, z=1e30f;
      ins3(x,y,z,v0); ins3(x,y,z,v1); ins3(x,y,z,v2); ins3(x,y,z,v3);
      #pragma unroll
      for (int m=1; m<16; m<<=1){
        const float ox = __shfl_xor(x, m);
        const float oy = __shfl_xor(y, m);
        const float oz = __shfl_xor(z, m);
        ins3(x,y,z,ox); ins3(x,y,z,oy); ins3(x,y,z,oz);
      }
      if ((l & 15) == 0){
        float* dst = wtop + ((size_t)(b*NA + n_g)*NCHUNK + (mi*2 + wc))*3;
        dst[0]=x; dst[1]=y; dst[2]=z;
      }
    }
  }
}

// ---------------------------------------------------------------------------
__global__ __launch_bounds__(256)
void merge_top3(const float* __restrict__ wtop, const float* __restrict__ wpos,
                float* __restrict__ partial){
  __shared__ float red[256];
  const int id = blockIdx.x*256 + threadIdx.x;
  const float* src = wtop + (size_t)id*(NCHUNK*3);
  float x=1e30f, y=1e30f, z=1e30f;
  #pragma unroll
  for (int i=0;i<NCHUNK*3;i++) ins3(x,y,z, src[i]);
  const float loss = fmaxf((x+y+z) - wpos[id] + MARGIN, 0.0f);
  red[threadIdx.x] = loss;
  __syncthreads();
  for (int s=128; s>0; s>>=1){
    if (threadIdx.x < s) red[threadIdx.x] += red[threadIdx.x+s];
    __syncthreads();
  }
  if (threadIdx.x == 0) partial[blockIdx.x] = red[0];
}

__global__ void final_sum(const float* __restrict__ partial, float* __restrict__ out){
  float v = partial[threadIdx.x];
  #pragma unroll
  for (int off=32; off>0; off>>=1) v += __shfl_down(v, off);
  if (threadIdx.x == 0) out[0] = v / (1e-6f + (float)NTOT);
}

// ---------------------------------------------------------------------------
extern "C" void kernel_launch(void* const* d_in, const int* in_sizes, int n_in,
                              void* d_out, int out_size, void* d_ws, size_t ws_size,
                              hipStream_t stream){
  const float* sketch = (const float*)d_in[0];
  const float* refk   = (const float*)d_in[1];
  const int*   anchor = (const int*)d_in[2];
  const int*   posidx = (const int*)d_in[3];
  float* out = (float*)d_out;

  float* wtop    = (float*)d_ws;                       // NTOT*NCHUNK*3 floats
  float* wpos    = wtop + (size_t)NTOT*NCHUNK*3;       // NTOT floats
  float* partial = wpos + NTOT;                        // 64 floats (+pad)
  unsigned short* tS = (unsigned short*)(partial + 256);
  unsigned short* tR = tS + (size_t)BATCH*HW*CDIM;
  float* pnorm = (float*)(tR + (size_t)BATCH*HW*CDIM); // 32*8*1024 floats
  float* snorm = pnorm + (size_t)32*8*1024;            // 32*1024 floats
  const size_t need = (size_t)((char*)(snorm + 32*1024) - (char*)d_ws);

  if (ws_size >= need){
    convert_transpose3<<<dim3(2048), dim3(256), 0, stream>>>(sketch, refk, tS, tR, pnorm);
    norm_reduce<<<dim3(32), dim3(256), 0, stream>>>(pnorm, snorm);
    fused_gemm_top3_v9<<<dim3(256), dim3(512), 0, stream>>>(tS, tR, snorm, anchor, posidx, wtop, wpos);
  } else {
    fused_gemm_top3_v1<<<dim3(1024), dim3(256), 0, stream>>>(sketch, refk, anchor, posidx, wtop, wpos);
  }
  merge_top3<<<dim3(64), dim3(256), 0, stream>>>(wtop, wpos, partial);
  final_sum<<<dim3(1), dim3(64), 0, stream>>>(partial, out);
}

// Round 14
// 95.099 us; speedup vs baseline: 1.1963x; 1.0226x over previous
//
#include <hip/hip_runtime.h>
#include <hip/hip_bf16.h>
#include <stdint.h>

// ---------------- problem constants ----------------
#define BATCH 16
#define CDIM  1024
#define FWID  32
#define HW    1024
#define NA    1024
#define NTOT  (BATCH*NA)    // 16384
#define NCHUNK 16           // 4 mi-tiles * 4 wc waves = 16 chunks of 64 cols
#define MARGIN 0.6f

typedef __bf16 bf16x8 __attribute__((ext_vector_type(8)));
typedef float  f32x4  __attribute__((ext_vector_type(4)));
typedef unsigned short us4 __attribute__((ext_vector_type(4)));
typedef unsigned short us8 __attribute__((ext_vector_type(8)));
typedef float  f4     __attribute__((ext_vector_type(4)));

template<int OFF>
__device__ __forceinline__ us4 tr_read(uint32_t addr){
  us4 r;
  asm volatile("ds_read_b64_tr_b16 %0, %1 offset:%2" : "=v"(r) : "v"(addr), "n"(OFF));
  return r;
}

__device__ __forceinline__ void gload16(const unsigned short* g, unsigned short* l){
  __builtin_amdgcn_global_load_lds((const __attribute__((address_space(1))) void*)g,
                                   (__attribute__((address_space(3))) void*)l, 16, 0, 0);
}

union FragU  { us4 h[2]; bf16x8 v; };
union FragU8 { us8 u;    bf16x8 v; };

__device__ __forceinline__ void ins3(float& a, float& b, float& c, float v){
  if (v < c){
    c = v;
    if (c < b){ float t=b; b=c; c=t;
      if (b < a){ t=a; a=b; b=t; }
    }
  }
}

#define MFMA __builtin_amdgcn_mfma_f32_16x16x32_bf16

// ---------------------------------------------------------------------------
// Pass 1 (v4): fp32 [c][hw] -> bf16 [hw][c].  Full 64x1024 transposed tile
// staged in LDS; global WRITES fully dense (128 KB contiguous per block,
// 1 KB per store instruction).  Reads unchanged vs v3 (isolates write-side).
// Block also completes the per-hw norm -> writes snorm directly (sqrt).
// grid: e(2) x b(16) x hwT(16) = 512 blocks, 512 threads.
// ---------------------------------------------------------------------------
__global__ __launch_bounds__(512)
void convert_transpose4(const float* __restrict__ S, const float* __restrict__ R,
                        unsigned short* __restrict__ tS, unsigned short* __restrict__ tR,
                        float* __restrict__ snorm){
  __shared__ unsigned short tile[64*1032];   // 132,096 B (pad 8 us/row)
  __shared__ float nsq[64][33];              // 8,448 B

  const int blk = blockIdx.x;
  const int e   = blk >> 8;
  const int b   = (blk >> 4) & 15;
  const int hwT = blk & 15;
  const float* src = (e ? R : S) + (size_t)b*CDIM*HW;
  unsigned short* dst = (e ? tR : tS) + (size_t)b*HW*CDIM;

  const int t  = threadIdx.x;
  const int li = t & 15;          // hw quad: hw = hwT*64 + li*4 + j
  const int gi = t >> 4;          // c-octet group 0..31
  const int hwb = hwT*64 + li*4;

  float sq0=0.f, sq1=0.f, sq2=0.f, sq3=0.f;
  #pragma unroll
  for (int it = 0; it < 4; ++it){
    const int cb = it*256 + gi*8;
    f4 col[8];
    #pragma unroll
    for (int i = 0; i < 8; ++i)
      col[i] = *(const f4*)&src[(size_t)(cb + i)*HW + hwb];
    #pragma unroll
    for (int j = 0; j < 4; ++j){
      us8 pk;
      float sq = 0.f;
      #pragma unroll
      for (int i = 0; i < 8; ++i){
        __hip_bfloat16 h = __float2bfloat16(col[i][j]);
        pk[i] = __builtin_bit_cast(unsigned short, h);
        const float g = __bfloat162float(h);
        sq = fmaf(g, g, sq);
      }
      *(us8*)&tile[(li*4 + j)*1032 + cb] = pk;
      if (j==0) sq0+=sq; else if (j==1) sq1+=sq; else if (j==2) sq2+=sq; else sq3+=sq;
    }
  }
  nsq[li*4+0][gi] = sq0;
  nsq[li*4+1][gi] = sq1;
  nsq[li*4+2][gi] = sq2;
  nsq[li*4+3][gi] = sq3;
  __syncthreads();

  // write phase: wave w -> rows w*8..w*8+7; per row 2 x 1KB dense stores.
  const int w = t >> 6, l = t & 63;
  #pragma unroll
  for (int rr = 0; rr < 8; ++rr){
    const int row = w*8 + rr;
    const us8 v0 = *(const us8*)&tile[row*1032 + l*8];
    const us8 v1 = *(const us8*)&tile[row*1032 + 512 + l*8];
    unsigned short* drow = dst + (size_t)(hwT*64 + row)*CDIM;
    *(us8*)(drow + l*8)       = v0;
    *(us8*)(drow + 512 + l*8) = v1;
  }

  if (t < 64){
    float a = 0.f;
    #pragma unroll
    for (int g2 = 0; g2 < 32; ++g2) a += nsq[t][g2];
    snorm[(size_t)(e*16 + b)*HW + hwT*64 + t] = sqrtf(a);
  }
}

// ---------------------------------------------------------------------------
// Pass 2 (v9, unchanged from round 13): 256x256 / 8-wave, BK=64, 2 bufs
// (128 KB), ONE barrier per 64-K tile.  8-chunk XOR swizzle; each staged
// row is a contiguous 128B global segment.
// ---------------------------------------------------------------------------
__global__ __launch_bounds__(512, 2)
void fused_gemm_top3_v9(const unsigned short* __restrict__ tS,
                        const unsigned short* __restrict__ tR,
                        const float* __restrict__ snorm,
                        const int*   __restrict__ anchor,
                        const int*   __restrict__ posidx,
                        float* __restrict__ wtop,   // [NTOT][NCHUNK][3]
                        float* __restrict__ wpos)   // [NTOT]
{
  __shared__ unsigned short stage[65536];
  __shared__ int   p_lds[256], q_lds[256];
  __shared__ float nAs[256], nBs[256];      // RECIPROCAL norms

  const int t = threadIdx.x;
  const uint32_t bid = blockIdx.x;
  const uint32_t L = (bid & 7u)*32u + (bid >> 3);   // XCD swizzle (256%8==0)
  const int b  = L >> 4;
  const int ni = (L >> 2) & 3;
  const int mi = L & 3;

  const unsigned short* SbT = tS + (size_t)b*HW*CDIM;
  const unsigned short* RbT = tR + (size_t)b*HW*CDIM;

  if (t < 256){
    const int n_g = ni*256 + t;
    const int* ap = anchor + (size_t)(b*NA + n_g)*3;
    const int* pp = posidx + (size_t)(b*NA + n_g)*3;
    const int pv = ap[2]*FWID + ap[1];
    p_lds[t] = pv;
    q_lds[t] = pp[2]*FWID + pp[1];
    nAs[t] = 1.0f / snorm[(size_t)b*HW + pv];
  } else {
    nBs[t-256] = 1.0f / snorm[(size_t)(BATCH + b)*HW + mi*256 + (t-256)];
  }
  __syncthreads();

  const int l  = t & 63;
  const int w  = t >> 6;
  const int wr = w >> 2, wc = w & 3;

  const int gkc = (l&7) ^ ((l>>3)&7);
  const unsigned short* gA[4];
  const unsigned short* gB[4];
  #pragma unroll
  for (int i = 0; i < 4; ++i){
    const int row = w*32 + i*8 + (l>>3);
    gA[i] = SbT + (size_t)p_lds[row]*CDIM + gkc*8;
    gB[i] = RbT + (size_t)(mi*256 + row)*CDIM + gkc*8;
  }
  unsigned short* lA = &stage[w*2048];
  unsigned short* lB = &stage[32768 + w*2048];

  const int fb0 = (l&15)*64 + (((l>>4)    ) ^ (l&7))*8;
  const int fb1 = (l&15)*64 + (((l>>4) + 4) ^ (l&7))*8;
  const int abase = wr*8192;            // wr*128 rows * 64 us
  const int bbase = 32768 + wc*4096;    // wc*64 rows * 64 us

  f32x4 acc[8][4];
  #pragma unroll
  for (int i=0;i<8;i++){
    #pragma unroll
    for (int j=0;j<4;j++){ f32x4 z = {0.f,0.f,0.f,0.f}; acc[i][j] = z; }
  }

  auto stage8 = [&](int bo, int kt){
    const int ko = kt*64;   // 128 B per row per tile
    #pragma unroll
    for (int i = 0; i < 4; ++i){
      gload16(gA[i] + ko, lA + bo + i*512);
      gload16(gB[i] + ko, lB + bo + i*512);
    }
  };

  auto half = [&](int bo, int fbh){
    FragU8 Bf[4], Af[8];
    #pragma unroll
    for (int fb=0; fb<4; ++fb) Bf[fb].u = *(const us8*)&stage[bbase + bo + fb*1024 + fbh];
    #pragma unroll
    for (int fa=0; fa<8; ++fa) Af[fa].u = *(const us8*)&stage[abase + bo + fa*1024 + fbh];
    __builtin_amdgcn_s_setprio(1);
    #pragma unroll
    for (int fa=0; fa<8; ++fa){
      #pragma unroll
      for (int fb=0; fb<4; ++fb)
        acc[fa][fb] = MFMA(Af[fa].v, Bf[fb].v, acc[fa][fb], 0,0,0);
    }
    __builtin_amdgcn_s_setprio(0);
  };

  // ---- main K loop: 16 tiles of BK=64, 2 bufs, 1 barrier/tile ----
  stage8(0, 0);
  int bo = 0;
  for (int kt = 0; kt < 16; ++kt){
    asm volatile("s_waitcnt vmcnt(0)" ::: "memory");  // tile kt landed (aged 1 full tile)
    __builtin_amdgcn_s_barrier();
    __builtin_amdgcn_sched_barrier(0);
    if (kt < 15) stage8(bo ^ 16384, kt+1);
    half(bo, fb0);
    half(bo, fb1);
    bo ^= 16384;
  }

  // ---- epilogue: reciprocal norms + LDS two-phase top3 (proven) ----
  __syncthreads();
  float* tls = (float*)&stage[0] + (size_t)w*1152;

  float rinv[4];
  #pragma unroll
  for (int fb=0; fb<4; ++fb) rinv[fb] = nBs[wc*64 + fb*16 + (l&15)];

  #pragma unroll
  for (int fa=0; fa<8; ++fa){
    #pragma unroll
    for (int r=0; r<4; ++r){
      const int rg    = (l>>4)*4 + r;
      const int row_l = wr*128 + fa*16 + rg;
      const float ain = nAs[row_l];
      const float v0 = acc[fa][0][r] * ain * rinv[0];
      const float v1 = acc[fa][1][r] * ain * rinv[1];
      const float v2 = acc[fa][2][r] * ain * rinv[2];
      const float v3 = acc[fa][3][r] * ain * rinv[3];

      const int n_g = ni*256 + row_l;
      const int q   = q_lds[row_l];
      const int ql  = q - (mi*256 + wc*64);
      if (ql >= 0 && ql < 64 && (ql & 15) == (l & 15)){
        const int sel = ql >> 4;
        const float pv = sel==0 ? v0 : sel==1 ? v1 : sel==2 ? v2 : v3;
        wpos[b*NA + n_g] = pv;
      }

      float x=1e30f, y=1e30f, z=1e30f;
      ins3(x,y,z,v0); ins3(x,y,z,v1); ins3(x,y,z,v2); ins3(x,y,z,v3);
      f4 tr = {x, y, z, 0.f};
      *(f4*)(tls + (rg*17 + (l&15))*4) = tr;
    }
    asm volatile("s_waitcnt lgkmcnt(0)" ::: "memory");
    __builtin_amdgcn_sched_barrier(0);

    {
      const int rr = l >> 2;
      const float* rbp = tls + (rr*17 + (l&3)*4)*4;
      const f4 t0 = *(const f4*)(rbp);
      const f4 t1 = *(const f4*)(rbp + 4);
      const f4 t2 = *(const f4*)(rbp + 8);
      const f4 t3 = *(const f4*)(rbp + 12);
      float x = t0[0], y = t0[1], z = t0[2];
      ins3(x,y,z,t1[0]); ins3(x,y,z,t1[1]); ins3(x,y,z,t1[2]);
      ins3(x,y,z,t2[0]); ins3(x,y,z,t2[1]); ins3(x,y,z,t2[2]);
      ins3(x,y,z,t3[0]); ins3(x,y,z,t3[1]); ins3(x,y,z,t3[2]);
      #pragma unroll
      for (int m=1; m<4; m<<=1){
        const float ox = __shfl_xor(x, m);
        const float oy = __shfl_xor(y, m);
        const float oz = __shfl_xor(z, m);
        ins3(x,y,z,ox); ins3(x,y,z,oy); ins3(x,y,z,oz);
      }
      if ((l & 3) == 0){
        const int n_g = ni*256 + wr*128 + fa*16 + rr;
        float* dst = wtop + ((size_t)(b*NA + n_g)*NCHUNK + (mi*4 + wc))*3;
        dst[0]=x; dst[1]=y; dst[2]=z;
      }
    }
    asm volatile("s_waitcnt lgkmcnt(0)" ::: "memory");
    __builtin_amdgcn_sched_barrier(0);
  }
}

// ---------------------------------------------------------------------------
// v1 (verified) fused kernel — fallback when workspace is too small.
// ---------------------------------------------------------------------------
__global__ __launch_bounds__(256)
void fused_gemm_top3_v1(const float* __restrict__ sketch,
                        const float* __restrict__ refk,
                        const int*   __restrict__ anchor,
                        const int*   __restrict__ posidx,
                        float* __restrict__ wtop,
                        float* __restrict__ wpos)
{
  __shared__ union {
    unsigned short stage[16384];
    struct { float nA[16][128]; float nB[16][128]; } nrm;
  } sh;
  __shared__ int   p_lds[128];
  __shared__ float nA2[128], nB2[128];

  const int t = threadIdx.x;
  const uint32_t bid = blockIdx.x;
  const uint32_t L = (bid & 7u)*128u + (bid >> 3);
  const int b  = L >> 6;
  const int ni = (L >> 3) & 7;
  const int mi = L & 7;

  const float* Sb = sketch + (size_t)b*CDIM*HW;
  const float* Rb = refk   + (size_t)b*CDIM*HW;

  if (t < 128){
    const int n_g = ni*128 + t;
    const int* ap = anchor + (size_t)(b*NA + n_g)*3;
    p_lds[t] = ap[2]*FWID + ap[1];
  }
  __syncthreads();
  const int p0 = p_lds[0];
  int okf = 1;
  if (t < 128) okf = (p_lds[t] == p0 + t);
  const int contig = __syncthreads_and(okf);

  const int colg = (t & 15)*8;
  const int rowg = t >> 4;
  const int mbase = mi*128;

  const int l  = t & 63;
  const int w  = t >> 6;
  const int wr = w >> 1, wc = w & 1;
  const uint32_t sh_base = (uint32_t)(uintptr_t)&sh.stage[0];
  const uint32_t laneA = ((uint32_t)(l>>4))*2048u + (uint32_t)wr*512u + (uint32_t)(l&15)*8u;
  const uint32_t laneB = ((uint32_t)(l>>4))*2048u + (uint32_t)wc*512u + (uint32_t)(l&15)*8u;
  const int off0 = ((rowg>>2)*8 + (colg>>4))*64 + (rowg&3)*16 + (colg&15);

  f32x4 acc[4][4];
  #pragma unroll
  for (int i=0;i<4;i++){
    #pragma unroll
    for (int j=0;j<4;j++){ f32x4 z = {0.f,0.f,0.f,0.f}; acc[i][j] = z; }
  }

  float sqA[8] = {0,0,0,0,0,0,0,0};
  float sqB[8] = {0,0,0,0,0,0,0,0};
  f4 ra[4], rb[4];

  auto load_tile = [&](int kt){
    const int c0 = kt*32 + rowg;
    const float* SA = Sb + (size_t)c0*HW;
    const float* RB = Rb + (size_t)c0*HW + mbase + colg;
    if (contig){
      const float* pA = SA + p0 + colg;
      ra[0] = *(const f4*)(pA);
      ra[1] = *(const f4*)(pA + 4);
      ra[2] = *(const f4*)(pA + 16*HW);
      ra[3] = *(const f4*)(pA + 16*HW + 4);
    } else {
      float* raf = (float*)ra;
      #pragma unroll
      for (int i=0;i<8;i++){
        const int pc = p_lds[colg + i];
        raf[i]   = SA[pc];
        raf[8+i] = SA[16*HW + pc];
      }
    }
    rb[0] = *(const f4*)(RB);
    rb[1] = *(const f4*)(RB + 4);
    rb[2] = *(const f4*)(RB + 16*HW);
    rb[3] = *(const f4*)(RB + 16*HW + 4);
  };

  auto cvt_store = [&](int buf){
    const float* raf = (const float*)ra;
    const float* rbf = (const float*)rb;
    us8 pk;
    #pragma unroll
    for (int i=0;i<8;i++){
      __hip_bfloat16 h = __float2bfloat16(raf[i]);
      pk[i] = __builtin_bit_cast(unsigned short, h);
      const float g = __bfloat162float(h);
      sqA[i] = fmaf(g, g, sqA[i]);
    }
    *(us8*)&sh.stage[buf*4096 + off0] = pk;
    #pragma unroll
    for (int i=0;i<8;i++){
      __hip_bfloat16 h = __float2bfloat16(raf[8+i]);
      pk[i] = __builtin_bit_cast(unsigned short, h);
      const float g = __bfloat162float(h);
      sqA[i] = fmaf(g, g, sqA[i]);
    }
    *(us8*)&sh.stage[buf*4096 + off0 + 2048] = pk;
    #pragma unroll
    for (int i=0;i<8;i++){
      __hip_bfloat16 h = __float2bfloat16(rbf[i]);
      pk[i] = __builtin_bit_cast(unsigned short, h);
      const float g = __bfloat162float(h);
      sqB[i] = fmaf(g, g, sqB[i]);
    }
    *(us8*)&sh.stage[8192 + buf*4096 + off0] = pk;
    #pragma unroll
    for (int i=0;i<8;i++){
      __hip_bfloat16 h = __float2bfloat16(rbf[8+i]);
      pk[i] = __builtin_bit_cast(unsigned short, h);
      const float g = __bfloat162float(h);
      sqB[i] = fmaf(g, g, sqB[i]);
    }
    *(us8*)&sh.stage[8192 + buf*4096 + off0 + 2048] = pk;
  };

  auto compute = [&](int buf){
    const uint32_t aaddr = sh_base + (uint32_t)buf*8192u + laneA;
    const uint32_t baddr = sh_base + 16384u + (uint32_t)buf*8192u + laneB;
    FragU A0,A1,A2,A3,B0,B1,B2,B3;
    A0.h[0]=tr_read<0>(aaddr);    A0.h[1]=tr_read<1024>(aaddr);
    A1.h[0]=tr_read<128>(aaddr);  A1.h[1]=tr_read<1152>(aaddr);
    A2.h[0]=tr_read<256>(aaddr);  A2.h[1]=tr_read<1280>(aaddr);
    A3.h[0]=tr_read<384>(aaddr);  A3.h[1]=tr_read<1408>(aaddr);
    B0.h[0]=tr_read<0>(baddr);    B0.h[1]=tr_read<1024>(baddr);
    B1.h[0]=tr_read<128>(baddr);  B1.h[1]=tr_read<1152>(baddr);
    B2.h[0]=tr_read<256>(baddr);  B2.h[1]=tr_read<1280>(baddr);
    B3.h[0]=tr_read<384>(baddr);  B3.h[1]=tr_read<1408>(baddr);
    asm volatile("s_waitcnt lgkmcnt(0)" ::: "memory");
    __builtin_amdgcn_sched_barrier(0);
    acc[0][0]=MFMA(A0.v,B0.v,acc[0][0],0,0,0);
    acc[0][1]=MFMA(A0.v,B1.v,acc[0][1],0,0,0);
    acc[0][2]=MFMA(A0.v,B2.v,acc[0][2],0,0,0);
    acc[0][3]=MFMA(A0.v,B3.v,acc[0][3],0,0,0);
    acc[1][0]=MFMA(A1.v,B0.v,acc[1][0],0,0,0);
    acc[1][1]=MFMA(A1.v,B1.v,acc[1][1],0,0,0);
    acc[1][2]=MFMA(A1.v,B2.v,acc[1][2],0,0,0);
    acc[1][3]=MFMA(A1.v,B3.v,acc[1][3],0,0,0);
    acc[2][0]=MFMA(A2.v,B0.v,acc[2][0],0,0,0);
    acc[2][1]=MFMA(A2.v,B1.v,acc[2][1],0,0,0);
    acc[2][2]=MFMA(A2.v,B2.v,acc[2][2],0,0,0);
    acc[2][3]=MFMA(A2.v,B3.v,acc[2][3],0,0,0);
    acc[3][0]=MFMA(A3.v,B0.v,acc[3][0],0,0,0);
    acc[3][1]=MFMA(A3.v,B1.v,acc[3][1],0,0,0);
    acc[3][2]=MFMA(A3.v,B2.v,acc[3][2],0,0,0);
    acc[3][3]=MFMA(A3.v,B3.v,acc[3][3],0,0,0);
  };

  load_tile(0);
  cvt_store(0);
  __syncthreads();
  int buf = 0;
  for (int kt = 0; kt < 32; ++kt){
    if (kt < 31) load_tile(kt+1);
    compute(buf);
    if (kt < 31) cvt_store(buf^1);
    __syncthreads();
    buf ^= 1;
  }

  #pragma unroll
  for (int i=0;i<8;i++) sh.nrm.nA[rowg][colg+i] = sqA[i];
  #pragma unroll
  for (int i=0;i<8;i++) sh.nrm.nB[rowg][colg+i] = sqB[i];
  __syncthreads();
  if (t < 128){
    float s = 0.f;
    #pragma unroll
    for (int r=0;r<16;r++) s += sh.nrm.nA[r][t];
    nA2[t] = s;
  } else {
    const int c2 = t - 128;
    float s = 0.f;
    #pragma unroll
    for (int r=0;r<16;r++) s += sh.nrm.nB[r][c2];
    nB2[c2] = s;
  }
  __syncthreads();

  float rncol[4];
  #pragma unroll
  for (int nf=0;nf<4;nf++) rncol[nf] = sqrtf(nB2[wc*64 + nf*16 + (l&15)]);

  #pragma unroll
  for (int mf=0; mf<4; ++mf){
    #pragma unroll
    for (int r=0; r<4; ++r){
      const int row_l = wr*64 + mf*16 + (l>>4)*4 + r;
      const int n_g   = ni*128 + row_l;
      const float an  = sqrtf(nA2[row_l]);
      const float v0 = acc[mf][0][r] / fmaxf(an*rncol[0], 1e-8f);
      const float v1 = acc[mf][1][r] / fmaxf(an*rncol[1], 1e-8f);
      const float v2 = acc[mf][2][r] / fmaxf(an*rncol[2], 1e-8f);
      const float v3 = acc[mf][3][r] / fmaxf(an*rncol[3], 1e-8f);

      const int* pp = posidx + (size_t)(b*NA + n_g)*3;
      const int q  = pp[2]*FWID + pp[1];
      const int ql = q - (mbase + wc*64);
      if (ql >= 0 && ql < 64 && (ql & 15) == (l & 15)){
        const int sel = ql >> 4;
        const float pv = sel==0 ? v0 : sel==1 ? v1 : sel==2 ? v2 : v3;
        wpos[b*NA + n_g] = pv;
      }

      float x=1e30f, y=1e30f, z=1e30f;
      ins3(x,y,z,v0); ins3(x,y,z,v1); ins3(x,y,z,v2); ins3(x,y,z,v3);
      #pragma unroll
      for (int m=1; m<16; m<<=1){
        const float ox = __shfl_xor(x, m);
        const float oy = __shfl_xor(y, m);
        const float oz = __shfl_xor(z, m);
        ins3(x,y,z,ox); ins3(x,y,z,oy); ins3(x,y,z,oz);
      }
      if ((l & 15) == 0){
        float* dst = wtop + ((size_t)(b*NA + n_g)*NCHUNK + (mi*2 + wc))*3;
        dst[0]=x; dst[1]=y; dst[2]=z;
      }
    }
  }
}

// ---------------------------------------------------------------------------
__global__ __launch_bounds__(256)
void merge_top3(const float* __restrict__ wtop, const float* __restrict__ wpos,
                float* __restrict__ partial){
  __shared__ float red[256];
  const int id = blockIdx.x*256 + threadIdx.x;
  const float* src = wtop + (size_t)id*(NCHUNK*3);
  float x=1e30f, y=1e30f, z=1e30f;
  #pragma unroll
  for (int i=0;i<NCHUNK*3;i++) ins3(x,y,z, src[i]);
  const float loss = fmaxf((x+y+z) - wpos[id] + MARGIN, 0.0f);
  red[threadIdx.x] = loss;
  __syncthreads();
  for (int s=128; s>0; s>>=1){
    if (threadIdx.x < s) red[threadIdx.x] += red[threadIdx.x+s];
    __syncthreads();
  }
  if (threadIdx.x == 0) partial[blockIdx.x] = red[0];
}

__global__ void final_sum(const float* __restrict__ partial, float* __restrict__ out){
  float v = partial[threadIdx.x];
  #pragma unroll
  for (int off=32; off>0; off>>=1) v += __shfl_down(v, off);
  if (threadIdx.x == 0) out[0] = v / (1e-6f + (float)NTOT);
}

// ---------------------------------------------------------------------------
extern "C" void kernel_launch(void* const* d_in, const int* in_sizes, int n_in,
                              void* d_out, int out_size, void* d_ws, size_t ws_size,
                              hipStream_t stream){
  const float* sketch = (const float*)d_in[0];
  const float* refk   = (const float*)d_in[1];
  const int*   anchor = (const int*)d_in[2];
  const int*   posidx = (const int*)d_in[3];
  float* out = (float*)d_out;

  float* wtop    = (float*)d_ws;                       // NTOT*NCHUNK*3 floats
  float* wpos    = wtop + (size_t)NTOT*NCHUNK*3;       // NTOT floats
  float* partial = wpos + NTOT;                        // 64 floats (+pad)
  unsigned short* tS = (unsigned short*)(partial + 256);
  unsigned short* tR = tS + (size_t)BATCH*HW*CDIM;
  float* snorm = (float*)(tR + (size_t)BATCH*HW*CDIM); // 32*1024 floats
  const size_t need = (size_t)((char*)(snorm + 32*1024) - (char*)d_ws);

  if (ws_size >= need){
    convert_transpose4<<<dim3(512), dim3(512), 0, stream>>>(sketch, refk, tS, tR, snorm);
    fused_gemm_top3_v9<<<dim3(256), dim3(512), 0, stream>>>(tS, tR, snorm, anchor, posidx, wtop, wpos);
  } else {
    fused_gemm_top3_v1<<<dim3(1024), dim3(256), 0, stream>>>(sketch, refk, anchor, posidx, wtop, wpos);
  }
  merge_top3<<<dim3(64), dim3(256), 0, stream>>>(wtop, wpos, partial);
  final_sum<<<dim3(1), dim3(64), 0, stream>>>(partial, out);
}